// Round 10
// baseline (721.781 us; speedup 1.0000x reference)
//
#include <hip/hip_runtime.h>
#include <hip/hip_bf16.h>
#include <hip/hip_cooperative_groups.h>

namespace cgns = cooperative_groups;

typedef __hip_bfloat16 bf16;

#define N_ATOMS 10000
#define N_EDGES 200000

// ======== float region of ws (float offsets) ========
#define SCG   0        // 615 cg coeffs f32
#define SINV  616      // 296 inv per channel (+pad)
#define SS1P  1024     // 64*296 partials [ab][ch]
#define SS2P  19968    // 5*64 partials
#define SWS2  20288    // 5 (+pad)
#define SINTS 20352    // int region starts here (float idx)
// ======== int region (offsets in ints, relative to SINTS) ========
#define IFLAG  0
#define ICOUNT 16      // 10000
#define IOFFS  10016   // 10001 (+pad)
#define ICURS  20032   // 10000
#define IBPART 30032   // 256 block partials (coop scan)
#define IBPREF 30288   // 256 block prefixes
#define IELIST 30544   // 400000 ints (int2 records)
#define INTS_END 430544
#define SXACC (SINTS + INTS_END)
#define BIG_FLOATS (SXACC + 952*N_ATOMS)      // ~39.9 MB

// ---- d_out element offsets ----
#define O0 0
#define O1 320000
#define O2 1040000
#define OY 1840000
#define OUT_ELEMS 5200000

__device__ __forceinline__ float b2f(bf16 x){ return __bfloat162float(x); }
__device__ __forceinline__ bf16  f2b(float x){ return __float2bfloat16(x); }

__device__ __forceinline__ float ldv(const float* p, int i){ return p[i]; }
__device__ __forceinline__ float ldv(const bf16*  p, int i){ return b2f(p[i]); }
__device__ __forceinline__ void  stv(float* p, int i, float v){ p[i] = v; }
__device__ __forceinline__ void  stv(bf16*  p, int i, float v){ p[i] = f2b(v); }

template<typename T> __device__ __forceinline__ int dtid();
template<> __device__ __forceinline__ int dtid<bf16>(){ return 0; }
template<> __device__ __forceinline__ int dtid<float>(){ return 1; }

struct Ptrs15 { const void* p[15]; };
struct LinP   { const void* W[5]; const void* B[5]; };

__constant__ int c_cg_sizes[15] = {1,9,25,9,9,27,45,45,75,25,45,75,25,75,125};
__constant__ int c_fin[5]   = {72,80,40,72,32};
__constant__ int c_kout[5]  = {32,24,24,16,16};
__constant__ int c_yoff[5]  = {OY+0, OY+320000, OY+1040000, OY+1760000, OY+2560000};
__constant__ int c_numel[5] = {320000,720000,720000,800000,800000};
__constant__ int c_cum[6]   = {0,32,104,176,256,336};
__constant__ int c_xb[5]    = {0,72,312,432,792};
__constant__ int c_Ms[5]    = {1,3,3,5,5};

// ---------------- fused cooperative prep: zero+probe+hist+scan+scatter+cg ---
__global__ void k_prep(float* wsf, int* wsi,
                       const unsigned short* rb0u, const unsigned short* embu,
                       const int* __restrict__ centers,
                       const int* __restrict__ neighbors,
                       Ptrs15 cgp, int know)
{
  cgns::grid_group grid = cgns::this_grid();
  int t = threadIdx.x;
  int tid = blockIdx.x*blockDim.x + t;
  int nthr = gridDim.x*blockDim.x;
  int* counts  = wsi + ICOUNT;
  int* offs    = wsi + IOFFS;
  int* cursors = wsi + ICURS;
  int* bpart   = wsi + IBPART;
  int* bpref   = wsi + IBPREF;
  int2* el2    = (int2*)(wsi + IELIST);

  // phase 0: zero + dtype probe
  if (blockIdx.x == 0 && t < 64) {
    int bad = 0;
    for (int i = t; i < 256; i += 64) {
      unsigned u1 = ((unsigned)rb0u[2*i]) << 16;
      unsigned u2 = ((unsigned)embu[2*i]) << 16;
      if (!(fabsf(__uint_as_float(u1)) < 1e9f) ||
          !(fabsf(__uint_as_float(u2)) < 1e9f)) bad = 1;
    }
    unsigned long long any = __ballot(bad);
    if (t == 0) wsi[IFLAG] = (any != 0ULL) ? 1 : 0;   // 1=fp32 0=bf16
  }
  for (int i = tid; i < N_ATOMS; i += nthr) { counts[i] = 0; cursors[i] = 0; }
  for (int i = tid; i < 18944; i += nthr) wsf[SS1P + i] = 0.f;
  for (int i = tid; i < 325;  i += nthr) wsf[SS2P + i] = 0.f;
  __threadfence();
  grid.sync();

  // phase 1: hist + cg f32 conversion
  for (int e = tid; e < N_EDGES; e += nthr) atomicAdd(&counts[centers[e]], 1);
  {
    int dt = (know >= 0) ? know : wsi[IFLAG];
    for (int i = tid; i < 615; i += nthr) {
      int s = 0, off = i;
      while (off >= c_cg_sizes[s]) { off -= c_cg_sizes[s]; ++s; }
      wsf[SCG + i] = (dt == 0) ? b2f(((const bf16*)cgp.p[s])[off])
                               : ((const float*)cgp.p[s])[off];
    }
  }
  __threadfence();
  grid.sync();

  // phase 2: two-level exclusive scan of counts -> offs
  __shared__ int sc[256];
  int c = (tid < N_ATOMS) ? counts[tid] : 0;
  sc[t] = c;
  __syncthreads();
  for (int d = 1; d < 256; d <<= 1) {
    int v = sc[t];
    int add = (t >= d) ? sc[t-d] : 0;
    __syncthreads();
    sc[t] = v + add;
    __syncthreads();
  }
  int incl = sc[t];
  if (t == 255) bpart[blockIdx.x] = incl;
  __threadfence();
  grid.sync();
  if (blockIdx.x == 0 && t == 0) {
    int run = 0;
    for (int b = 0; b < 256; ++b) { bpref[b] = run; run += bpart[b]; }
    offs[N_ATOMS] = run;
  }
  __threadfence();
  grid.sync();
  if (tid < N_ATOMS) offs[tid] = bpref[blockIdx.x] + incl - c;
  __threadfence();
  grid.sync();

  // phase 3: scatter (e, neighbor) records into center order
  for (int e = tid; e < N_EDGES; e += nthr) {
    int cc = centers[e];
    int p = atomicAdd(&cursors[cc], 1);
    el2[offs[cc] + p] = make_int2(e, neighbors[e]);
  }
}

// ---------------- legacy prep kernels (fallback if coop launch fails) -------
__global__ void k_zero(float* wsf, int* wsi,
                       const unsigned short* rb0u, const unsigned short* embu) {
  if (blockIdx.x == 0 && threadIdx.x < 64) {
    int lane = threadIdx.x;
    int bad = 0;
    for (int i = lane; i < 256; i += 64) {
      unsigned u1 = ((unsigned)rb0u[2*i]) << 16;
      unsigned u2 = ((unsigned)embu[2*i]) << 16;
      float v1 = __uint_as_float(u1);
      float v2 = __uint_as_float(u2);
      if (!(fabsf(v1) < 1e9f) || !(fabsf(v2) < 1e9f)) bad = 1;
    }
    unsigned long long any = __ballot(bad);
    if (lane == 0) wsi[IFLAG] = (any != 0ULL) ? 1 : 0;
  }
  int i = blockIdx.x*blockDim.x + threadIdx.x;
  if (i < N_ATOMS) wsi[ICOUNT + i] = 0;
  int j = i - N_ATOMS;
  if (j >= 0 && j < N_ATOMS) wsi[ICURS + j] = 0;
  j -= N_ATOMS;
  if (j >= 0 && j < 18944) wsf[SS1P + j] = 0.f;
  j -= 18944;
  if (j >= 0 && j < 325) wsf[SS2P + j] = 0.f;
}

template<typename T>
__global__ void k_cg(Ptrs15 cg, float* wsf, const int* flag) {
  if (flag[0] != dtid<T>()) return;
  int i = blockIdx.x*blockDim.x + threadIdx.x;
  if (i >= 615) return;
  int s = 0, off = i;
  while (off >= c_cg_sizes[s]) { off -= c_cg_sizes[s]; ++s; }
  wsf[SCG + i] = ldv((const T*)cg.p[s], off);
}

__global__ void k_hist(const int* __restrict__ centers, int* __restrict__ counts) {
  int e = blockIdx.x*blockDim.x + threadIdx.x;
  if (e < N_EDGES) atomicAdd(&counts[centers[e]], 1);
}

__global__ void k_scan(const int* __restrict__ counts, int* __restrict__ offs) {
  __shared__ int part[1024];
  int t = threadIdx.x;
  int base = t*10;
  int s = 0;
  for (int i = 0; i < 10; ++i) { int idx = base+i; if (idx < N_ATOMS) s += counts[idx]; }
  part[t] = s;
  __syncthreads();
  for (int d = 1; d < 1024; d <<= 1) {
    int v = part[t];
    int add = (t >= d) ? part[t-d] : 0;
    __syncthreads();
    part[t] = v + add;
    __syncthreads();
  }
  int run = (t == 0) ? 0 : part[t-1];
  for (int i = 0; i < 10; ++i) {
    int idx = base+i;
    if (idx < N_ATOMS) { offs[idx] = run; run += counts[idx]; }
  }
  if (t == 1023) offs[N_ATOMS] = part[1023];
}

__global__ void k_scatter2(const int* __restrict__ centers, const int* __restrict__ neighbors,
                           const int* __restrict__ offs, int* __restrict__ cursors,
                           int2* __restrict__ elist2) {
  int e = blockIdx.x*blockDim.x + threadIdx.x;
  if (e < N_EDGES) {
    int c = centers[e];
    int p = atomicAdd(&cursors[c], 1);
    elist2[offs[c] + p] = make_int2(e, neighbors[e]);
  }
}

// ---------------- role kernel (big path) -- R9 shape, proven best -----------
// ONE atom per 320-thread block (5 role-waves co-located: L1 dedupe of edge
// rows, write-combining of the xg record). 32-VGPR template body. No barriers,
// no LDS. XCD swizzle (bijective: 10000 = 8*1250).
template<typename T>
__global__ __launch_bounds__(320, 8) void k_role(
    const T* __restrict__ rb0, const T* __restrict__ rb1, const T* __restrict__ rb2,
    const T* __restrict__ sh0, const T* __restrict__ sh1, const T* __restrict__ sh2,
    const T* __restrict__ emb, const T* __restrict__ f0, const T* __restrict__ f1,
    const T* __restrict__ f2, const int2* __restrict__ el2,
    const int* __restrict__ offs, const float* __restrict__ cgf,
    float* __restrict__ s1p, float* __restrict__ xout, T* __restrict__ out,
    const int* __restrict__ flag)
{
  if (flag[0] != dtid<T>()) return;
  int lane = threadIdx.x & 63;
  int role = threadIdx.x >> 6;                 // 0..4
  int xcd = blockIdx.x & 7;
  int al  = blockIdx.x >> 3;                   // 0..1249
  int a = al * 8 + xcd;                        // bijective over 10000
  int beg = offs[a];
  int cnt = offs[a+1] - beg;
  const int2* eb = el2 + beg;
  int ab = a & 63;
  int k32 = lane & 31, e2 = lane >> 5;
  int k16 = lane & 15, e4 = lane >> 4;
  float* xg = xout + a*952;
  float* s1r = s1p + ab*296;

  if (role == 0) {
    float acc[8];
    #pragma unroll
    for (int i = 0; i < 8; ++i) acc[i] = 0.f;
    for (int base = 0; base < cnt; base += 4) {
      #pragma unroll
      for (int u = 0; u < 2; ++u) {
        int idx = base + 2*u + e2;
        float w = (idx < cnt) ? 1.f : 0.f;
        int ic  = (idx < cnt) ? idx : 0;
        int2 en = eb[ic];
        int e = en.x, n = en.y;
        float s0 = ldv(sh0, e);
        float s1a0 = ldv(sh1, e*3+0), s1a1 = ldv(sh1, e*3+1), s1a2 = ldv(sh1, e*3+2);
        float rb0k = ldv(rb0, e*32 + k32) * w;
        float ek   = ldv(emb, n*32 + k32);
        float f0k  = ldv(f0,  n*32 + k32);
        float ve0 = s0 * rb0k;
        acc[0] = fmaf(ve0, ek, acc[0]);
        acc[4] = fmaf(ve0, f0k, acc[4]);
        if (k32 < 24) {
          float rb1k = ldv(rb1, e*24 + k32) * w;
          float rbek = rb1k * ek;
          acc[1] = fmaf(s1a0, rbek, acc[1]);
          acc[2] = fmaf(s1a1, rbek, acc[2]);
          acc[3] = fmaf(s1a2, rbek, acc[3]);
          float f1k0 = ldv(f1, n*72 + k32);
          float f1k1 = ldv(f1, n*72 + 24 + k32);
          float f1k2 = ldv(f1, n*72 + 48 + k32);
          acc[5] = fmaf(ve0, f1k0, acc[5]);
          acc[6] = fmaf(ve0, f1k1, acc[6]);
          acc[7] = fmaf(ve0, f1k2, acc[7]);
        }
      }
    }
    #pragma unroll
    for (int i = 0; i < 8; ++i) acc[i] += __shfl_xor(acc[i], 32);
    const float* C011 = cgf + 1;
    float x000 = cgf[0] * acc[4];
    float x011[3];
    #pragma unroll
    for (int M = 0; M < 3; ++M) {
      float t = 0.f;
      #pragma unroll
      for (int b = 0; b < 3; ++b) t = fmaf(acc[5+b], C011[b*3+M], t);
      x011[M] = t;
    }
    if (lane < 32) {
      stv(out, O0 + a*32 + k32, acc[0]);
      xg[k32] = x000;
      atomicAdd(&s1r[k32], x000*x000);
      if (k32 < 24) {
        #pragma unroll
        for (int m = 0; m < 3; ++m) stv(out, O1 + a*72 + m*24 + k32, acc[1+m]);
        #pragma unroll
        for (int M = 0; M < 3; ++M) xg[72+M*80+k32] = x011[M];
        atomicAdd(&s1r[72+k32], x011[0]*x011[0]+x011[1]*x011[1]+x011[2]*x011[2]);
      }
    }
  } else if (role == 1) {
    float acc[12];
    #pragma unroll
    for (int i = 0; i < 12; ++i) acc[i] = 0.f;
    int k24 = (k32 < 24) ? k32 : 23;
    float m24 = (k32 < 24) ? 1.f : 0.f;
    for (int base = 0; base < cnt; base += 4) {
      #pragma unroll
      for (int u = 0; u < 2; ++u) {
        int idx = base + 2*u + e2;
        float w = ((idx < cnt) ? 1.f : 0.f) * m24;
        int ic  = (idx < cnt) ? idx : 0;
        int2 en = eb[ic];
        int e = en.x, n = en.y;
        float s1a0 = ldv(sh1, e*3+0), s1a1 = ldv(sh1, e*3+1), s1a2 = ldv(sh1, e*3+2);
        float rb1k = ldv(rb1, e*24 + k24) * w;
        float f0k  = ldv(f0,  n*32 + k24);
        float f1k0 = ldv(f1, n*72 + k24);
        float f1k1 = ldv(f1, n*72 + 24 + k24);
        float f1k2 = ldv(f1, n*72 + 48 + k24);
        float g3 = rb1k * f0k;
        acc[0] = fmaf(g3, s1a0, acc[0]);
        acc[1] = fmaf(g3, s1a1, acc[1]);
        acc[2] = fmaf(g3, s1a2, acc[2]);
        float sa;
        sa = rb1k * s1a0;
        acc[3] = fmaf(sa, f1k0, acc[3]); acc[4] = fmaf(sa, f1k1, acc[4]); acc[5] = fmaf(sa, f1k2, acc[5]);
        sa = rb1k * s1a1;
        acc[6] = fmaf(sa, f1k0, acc[6]); acc[7] = fmaf(sa, f1k1, acc[7]); acc[8] = fmaf(sa, f1k2, acc[8]);
        sa = rb1k * s1a2;
        acc[9] = fmaf(sa, f1k0, acc[9]); acc[10] = fmaf(sa, f1k1, acc[10]); acc[11] = fmaf(sa, f1k2, acc[11]);
      }
    }
    #pragma unroll
    for (int i = 0; i < 12; ++i) acc[i] += __shfl_xor(acc[i], 32);
    const float* C101 = cgf + 35;
    const float* C110 = cgf + 44;
    const float* C111 = cgf + 53;
    const float* C112 = cgf + 80;
    float x101[3], x111[3], x112[5], x110;
    #pragma unroll
    for (int M = 0; M < 3; ++M) {
      float t = 0.f;
      #pragma unroll
      for (int aa = 0; aa < 3; ++aa) t = fmaf(acc[aa], C101[aa*3+M], t);
      x101[M] = t;
    }
    {
      float t = 0.f;
      #pragma unroll
      for (int q = 0; q < 9; ++q) t = fmaf(acc[3+q], C110[q], t);
      x110 = t;
    }
    #pragma unroll
    for (int M = 0; M < 3; ++M) {
      float t = 0.f;
      #pragma unroll
      for (int q = 0; q < 9; ++q) t = fmaf(acc[3+q], C111[q*3+M], t);
      x111[M] = t;
    }
    #pragma unroll
    for (int M = 0; M < 5; ++M) {
      float t = 0.f;
      #pragma unroll
      for (int q = 0; q < 9; ++q) t = fmaf(acc[3+q], C112[q*5+M], t);
      x112[M] = t;
    }
    if (lane < 24) {
      xg[32+k32] = x110;
      #pragma unroll
      for (int M = 0; M < 3; ++M) xg[72+M*80+24+k32] = x101[M];
      #pragma unroll
      for (int M = 0; M < 3; ++M) xg[312+M*40+k32]   = x111[M];
      #pragma unroll
      for (int M = 0; M < 5; ++M) xg[432+M*72+16+k32] = x112[M];
      atomicAdd(&s1r[32+k32], x110*x110);
      atomicAdd(&s1r[96+k32], x101[0]*x101[0]+x101[1]*x101[1]+x101[2]*x101[2]);
      atomicAdd(&s1r[152+k32], x111[0]*x111[0]+x111[1]*x111[1]+x111[2]*x111[2]);
      atomicAdd(&s1r[208+k32], x112[0]*x112[0]+x112[1]*x112[1]+x112[2]*x112[2]
                              + x112[3]*x112[3]+x112[4]*x112[4]);
    }
  } else if (role == 2) {
    float acc[25];
    #pragma unroll
    for (int i = 0; i < 25; ++i) acc[i] = 0.f;
    for (int base = 0; base < cnt; base += 8) {
      #pragma unroll
      for (int u = 0; u < 2; ++u) {
        int idx = base + 4*u + e4;
        float w = (idx < cnt) ? 1.f : 0.f;
        int ic  = (idx < cnt) ? idx : 0;
        int2 en = eb[ic];
        int e = en.x, n = en.y;
        float s0 = ldv(sh0, e);
        float s1a[3];
        #pragma unroll
        for (int m = 0; m < 3; ++m) s1a[m] = ldv(sh1, e*3+m);
        float s2a[5];
        #pragma unroll
        for (int m = 0; m < 5; ++m) s2a[m] = ldv(sh2, e*5+m);
        float rb0k = ldv(rb0, e*32 + k16) * w;
        float rb1k = ldv(rb1, e*24 + k16) * w;
        float rb2k = ldv(rb2, e*16 + k16) * w;
        float ek   = ldv(emb, n*32 + k16);
        float f2k[5];
        #pragma unroll
        for (int b = 0; b < 5; ++b) f2k[b] = ldv(f2, n*80 + b*16 + k16);
        float re = rb2k * ek;
        #pragma unroll
        for (int m = 0; m < 5; ++m) acc[m] = fmaf(s2a[m], re, acc[m]);
        float ve0 = s0 * rb0k;
        #pragma unroll
        for (int b = 0; b < 5; ++b) acc[5+b] = fmaf(ve0, f2k[b], acc[5+b]);
        #pragma unroll
        for (int aa = 0; aa < 3; ++aa) {
          float sa = rb1k * s1a[aa];
          #pragma unroll
          for (int b = 0; b < 5; ++b)
            acc[10+aa*5+b] = fmaf(sa, f2k[b], acc[10+aa*5+b]);
        }
      }
    }
    #pragma unroll
    for (int i = 0; i < 25; ++i) {
      acc[i] += __shfl_xor(acc[i], 16);
      acc[i] += __shfl_xor(acc[i], 32);
    }
    const float* C022 = cgf + 10;
    const float* C121 = cgf + 125;
    const float* C122 = cgf + 170;
    float x022[5], x121[3], x122[5];
    #pragma unroll
    for (int M = 0; M < 5; ++M) {
      float t = 0.f;
      #pragma unroll
      for (int b = 0; b < 5; ++b) t = fmaf(acc[5+b], C022[b*5+M], t);
      x022[M] = t;
    }
    #pragma unroll
    for (int M = 0; M < 3; ++M) {
      float t = 0.f;
      #pragma unroll
      for (int q = 0; q < 15; ++q) t = fmaf(acc[10+q], C121[q*3+M], t);
      x121[M] = t;
    }
    #pragma unroll
    for (int M = 0; M < 5; ++M) {
      float t = 0.f;
      #pragma unroll
      for (int q = 0; q < 15; ++q) t = fmaf(acc[10+q], C122[q*5+M], t);
      x122[M] = t;
    }
    if (lane < 16) {
      #pragma unroll
      for (int m = 0; m < 5; ++m) stv(out, O2 + a*80 + m*16 + k16, acc[m]);
      #pragma unroll
      for (int M = 0; M < 5; ++M) xg[432+M*72+k16]   = x022[M];
      #pragma unroll
      for (int M = 0; M < 3; ++M) xg[72+M*80+48+k16] = x121[M];
      #pragma unroll
      for (int M = 0; M < 5; ++M) xg[792+M*32+k16]   = x122[M];
      atomicAdd(&s1r[192+k16], x022[0]*x022[0]+x022[1]*x022[1]+x022[2]*x022[2]
                              + x022[3]*x022[3]+x022[4]*x022[4]);
      atomicAdd(&s1r[120+k16], x121[0]*x121[0]+x121[1]*x121[1]+x121[2]*x121[2]);
      atomicAdd(&s1r[264+k16], x122[0]*x122[0]+x122[1]*x122[1]+x122[2]*x122[2]
                              + x122[3]*x122[3]+x122[4]*x122[4]);
    }
  } else if (role == 3) {
    float acc[20];
    #pragma unroll
    for (int i = 0; i < 20; ++i) acc[i] = 0.f;
    for (int base = 0; base < cnt; base += 8) {
      #pragma unroll
      for (int u = 0; u < 2; ++u) {
        int idx = base + 4*u + e4;
        float w = (idx < cnt) ? 1.f : 0.f;
        int ic  = (idx < cnt) ? idx : 0;
        int2 en = eb[ic];
        int e = en.x, n = en.y;
        float s2a[5];
        #pragma unroll
        for (int m = 0; m < 5; ++m) s2a[m] = ldv(sh2, e*5+m);
        float rb2k = ldv(rb2, e*16 + k16) * w;
        float f0k  = ldv(f0,  n*32 + k16);
        float f1k[3];
        #pragma unroll
        for (int b = 0; b < 3; ++b) f1k[b] = ldv(f1, n*72 + b*24 + k16);
        float g9 = rb2k * f0k;
        #pragma unroll
        for (int aa = 0; aa < 5; ++aa) acc[aa] = fmaf(g9, s2a[aa], acc[aa]);
        #pragma unroll
        for (int aa = 0; aa < 5; ++aa) {
          float sa = rb2k * s2a[aa];
          #pragma unroll
          for (int b = 0; b < 3; ++b)
            acc[5+aa*3+b] = fmaf(sa, f1k[b], acc[5+aa*3+b]);
        }
      }
    }
    #pragma unroll
    for (int i = 0; i < 20; ++i) {
      acc[i] += __shfl_xor(acc[i], 16);
      acc[i] += __shfl_xor(acc[i], 32);
    }
    const float* C202 = cgf + 245;
    const float* C211 = cgf + 270;
    const float* C212 = cgf + 315;
    float x202[5], x211[3], x212[5];
    #pragma unroll
    for (int M = 0; M < 5; ++M) {
      float t = 0.f;
      #pragma unroll
      for (int aa = 0; aa < 5; ++aa) t = fmaf(acc[aa], C202[aa*5+M], t);
      x202[M] = t;
    }
    #pragma unroll
    for (int M = 0; M < 3; ++M) {
      float t = 0.f;
      #pragma unroll
      for (int q = 0; q < 15; ++q) t = fmaf(acc[5+q], C211[q*3+M], t);
      x211[M] = t;
    }
    #pragma unroll
    for (int M = 0; M < 5; ++M) {
      float t = 0.f;
      #pragma unroll
      for (int q = 0; q < 15; ++q) t = fmaf(acc[5+q], C212[q*5+M], t);
      x212[M] = t;
    }
    if (lane < 16) {
      #pragma unroll
      for (int M = 0; M < 5; ++M) xg[432+M*72+40+k16] = x202[M];
      #pragma unroll
      for (int M = 0; M < 3; ++M) xg[72+M*80+64+k16]  = x211[M];
      #pragma unroll
      for (int M = 0; M < 5; ++M) xg[792+M*32+16+k16] = x212[M];
      atomicAdd(&s1r[232+k16], x202[0]*x202[0]+x202[1]*x202[1]+x202[2]*x202[2]
                              + x202[3]*x202[3]+x202[4]*x202[4]);
      atomicAdd(&s1r[136+k16], x211[0]*x211[0]+x211[1]*x211[1]+x211[2]*x211[2]);
      atomicAdd(&s1r[280+k16], x212[0]*x212[0]+x212[1]*x212[1]+x212[2]*x212[2]
                              + x212[3]*x212[3]+x212[4]*x212[4]);
    }
  } else {
    float acc[25];
    #pragma unroll
    for (int i = 0; i < 25; ++i) acc[i] = 0.f;
    for (int base = 0; base < cnt; base += 8) {
      #pragma unroll
      for (int u = 0; u < 2; ++u) {
        int idx = base + 4*u + e4;
        float w = (idx < cnt) ? 1.f : 0.f;
        int ic  = (idx < cnt) ? idx : 0;
        int2 en = eb[ic];
        int e = en.x, n = en.y;
        float s2a[5];
        #pragma unroll
        for (int m = 0; m < 5; ++m) s2a[m] = ldv(sh2, e*5+m);
        float rb2k = ldv(rb2, e*16 + k16) * w;
        float f2k[5];
        #pragma unroll
        for (int b = 0; b < 5; ++b) f2k[b] = ldv(f2, n*80 + b*16 + k16);
        #pragma unroll
        for (int aa = 0; aa < 5; ++aa) {
          float sa = rb2k * s2a[aa];
          #pragma unroll
          for (int b = 0; b < 5; ++b)
            acc[aa*5+b] = fmaf(sa, f2k[b], acc[aa*5+b]);
        }
      }
    }
    #pragma unroll
    for (int i = 0; i < 25; ++i) {
      acc[i] += __shfl_xor(acc[i], 16);
      acc[i] += __shfl_xor(acc[i], 32);
    }
    const float* C220 = cgf + 390;
    const float* C221 = cgf + 415;
    const float* C222 = cgf + 490;
    float x220, x221[3], x222[5];
    {
      float t = 0.f;
      #pragma unroll
      for (int q = 0; q < 25; ++q) t = fmaf(acc[q], C220[q], t);
      x220 = t;
    }
    #pragma unroll
    for (int M = 0; M < 3; ++M) {
      float t = 0.f;
      #pragma unroll
      for (int q = 0; q < 25; ++q) t = fmaf(acc[q], C221[q*3+M], t);
      x221[M] = t;
    }
    #pragma unroll
    for (int M = 0; M < 5; ++M) {
      float t = 0.f;
      #pragma unroll
      for (int q = 0; q < 25; ++q) t = fmaf(acc[q], C222[q*5+M], t);
      x222[M] = t;
    }
    if (lane < 16) {
      xg[56+k16] = x220;
      #pragma unroll
      for (int M = 0; M < 3; ++M) xg[312+M*40+24+k16] = x221[M];
      #pragma unroll
      for (int M = 0; M < 5; ++M) xg[432+M*72+56+k16] = x222[M];
      atomicAdd(&s1r[56+k16], x220*x220);
      atomicAdd(&s1r[176+k16], x221[0]*x221[0]+x221[1]*x221[1]+x221[2]*x221[2]);
      atomicAdd(&s1r[248+k16], x222[0]*x222[0]+x222[1]*x222[1]+x222[2]*x222[2]
                              + x222[3]*x222[3]+x222[4]*x222[4]);
    }
  }
}

// ---------------- big path: normalize + linear from stored x ----------------
template<typename T>
__device__ __forceinline__ void lin_body(
    const float* __restrict__ xg, const float* __restrict__ inv,
    LinP lp, T* __restrict__ out, float* __restrict__ s2p)
{
  int a = blockIdx.x;
  int t = threadIdx.x;
  __shared__ float L[952];
  for (int i = t; i < 952; i += 256) {
    int ch;
    if      (i < 72)  ch = i;
    else if (i < 312) ch = 72  + (i-72)  % 80;
    else if (i < 432) ch = 152 + (i-312) % 40;
    else if (i < 792) ch = 192 + (i-432) % 72;
    else              ch = 264 + (i-792) % 32;
    L[i] = xg[a*952 + i] * inv[ch];
  }
  __syncthreads();
  float y2[5] = {0.f,0.f,0.f,0.f,0.f};
  for (int tau = t; tau < 336; tau += 256) {
    int ls = 0;
    while (tau >= c_cum[ls+1]) ++ls;
    int rem = tau - c_cum[ls];
    int kn = c_kout[ls], fin = c_fin[ls];
    int M = rem / kn, ko = rem - M*kn;
    const T* W = (const T*)lp.W[ls];
    float y = ldv((const T*)lp.B[ls], ko);
    const float* xv = &L[c_xb[ls] + M*fin];
    for (int f = 0; f < fin; ++f) y = fmaf(xv[f], ldv(W, f*kn+ko), y);
    stv(out, c_yoff[ls] + (a*c_Ms[ls] + M)*kn + ko, y);
    y2[ls] += y*y;
  }
  __shared__ float red[4][5];
  #pragma unroll
  for (int i = 0; i < 5; ++i) {
    y2[i] += __shfl_xor(y2[i], 1);  y2[i] += __shfl_xor(y2[i], 2);
    y2[i] += __shfl_xor(y2[i], 4);  y2[i] += __shfl_xor(y2[i], 8);
    y2[i] += __shfl_xor(y2[i], 16); y2[i] += __shfl_xor(y2[i], 32);
  }
  if ((t & 63) == 0) {
    #pragma unroll
    for (int i = 0; i < 5; ++i) red[t>>6][i] = y2[i];
  }
  __syncthreads();
  if (t == 0) {
    #pragma unroll
    for (int i = 0; i < 5; ++i)
      atomicAdd(&s2p[i*64 + (a & 63)], red[0][i]+red[1][i]+red[2][i]+red[3][i]);
  }
}

__global__ __launch_bounds__(256) void k_lin(
    const float* __restrict__ xg, const float* __restrict__ inv,
    LinP lp, void* outv, float* __restrict__ s2p,
    const int* __restrict__ flag, int know)
{
  int dt = (know >= 0) ? know : flag[0];
  if (dt == 0) lin_body<bf16>(xg, inv, lp, (bf16*)outv, s2p);
  else         lin_body<float>(xg, inv, lp, (float*)outv, s2p);
}

// ---------------- reducer for s1p ----------------
__global__ void k_red1(const float* __restrict__ s1p, float* __restrict__ inv) {
  int ch = blockIdx.x, lane = threadIdx.x;
  float v = s1p[lane*296 + ch];
  v += __shfl_xor(v, 1);  v += __shfl_xor(v, 2);  v += __shfl_xor(v, 4);
  v += __shfl_xor(v, 8);  v += __shfl_xor(v, 16); v += __shfl_xor(v, 32);
  if (lane == 0) {
    float rows = (ch < 72) ? 10000.f : (ch < 192) ? 30000.f : 50000.f;
    inv[ch] = rsqrtf(v/rows + 1e-12f);
  }
}

// ---------------- final global RMS scale (fused s2p reduction) --------------
__global__ __launch_bounds__(256) void k_scale(
    const float* __restrict__ s2p, void* outv,
    const int* __restrict__ flag, int know)
{
  __shared__ float ssum[5];
  int t = threadIdx.x;
  if (t < 64) {
    #pragma unroll
    for (int i = 0; i < 5; ++i) {
      float x = s2p[i*64 + t];
      x += __shfl_xor(x, 1);  x += __shfl_xor(x, 2);  x += __shfl_xor(x, 4);
      x += __shfl_xor(x, 8);  x += __shfl_xor(x, 16); x += __shfl_xor(x, 32);
      if (t == 0) ssum[i] = x;
    }
  }
  __syncthreads();
  int dt = (know >= 0) ? know : flag[0];
  int i = blockIdx.x*blockDim.x + t;
  if (i >= 3360000) return;
  int ls = (i < 320000) ? 0 : (i < 1040000) ? 1 : (i < 1760000) ? 2 : (i < 2560000) ? 3 : 4;
  float scale = rsqrtf(ssum[ls] / (float)c_numel[ls] + 1e-12f);
  if (dt == 0) { bf16* o = (bf16*)outv;  stv(o, OY+i, ldv((const bf16*)o,  OY+i) * scale); }
  else         { float* o = (float*)outv; stv(o, OY+i, ldv((const float*)o, OY+i) * scale); }
}

// ---------------- monolithic kernel (small-ws fallback only) ---------------
template<typename T, int MODE>
__global__ __launch_bounds__(256) void k_main(
    const T* __restrict__ rb0, const T* __restrict__ rb1, const T* __restrict__ rb2,
    const T* __restrict__ sh0, const T* __restrict__ sh1, const T* __restrict__ sh2,
    const T* __restrict__ emb, const T* __restrict__ f0, const T* __restrict__ f1,
    const T* __restrict__ f2, const int2* __restrict__ el2,
    const int* __restrict__ offs, const float* __restrict__ cgf,
    float* __restrict__ s1p, const float* __restrict__ inv,
    float* __restrict__ s2p, LinP lp, T* __restrict__ out,
    const int* __restrict__ flag)
{
  if (flag[0] != dtid<T>()) return;
  int lane = threadIdx.x & 63;
  int wv   = threadIdx.x >> 6;
  int tix  = threadIdx.x;
  int a = blockIdx.x;
  int beg = offs[a];
  int cnt = offs[a+1] - beg;
  int k32 = lane & 31, e2 = lane >> 5;
  int k16 = lane & 15, e4 = lane >> 4;
  int ab = a & 63;
  float* s1r = s1p + ab*296;

  __shared__ int2 sel[256];
  __shared__ __align__(16) float L[952];
  __shared__ float red[4][5];

  float acc[25];
  #pragma unroll
  for (int i = 0; i < 25; ++i) acc[i] = 0.f;

  for (int cbase = 0; cbase < cnt; cbase += 256) {
    int nch = cnt - cbase; if (nch > 256) nch = 256;
    __syncthreads();
    if (tix < nch) sel[tix] = el2[beg + cbase + tix];
    __syncthreads();

    if (wv == 0) {
      for (int base = 0; base < nch; base += 4) {
        #pragma unroll
        for (int u = 0; u < 2; ++u) {
          int idx = base + 2*u + e2;
          float w = (idx < nch) ? 1.f : 0.f;
          int ic  = (idx < nch) ? idx : 0;
          int2 en = sel[ic];
          int e = en.x, n = en.y;
          float s0 = ldv(sh0, e);
          float s1a0 = ldv(sh1, e*3+0), s1a1 = ldv(sh1, e*3+1), s1a2 = ldv(sh1, e*3+2);
          float rb0k = ldv(rb0, e*32 + k32) * w;
          float ek   = ldv(emb, n*32 + k32);
          float f0k  = ldv(f0,  n*32 + k32);
          float ve0 = s0 * rb0k;
          acc[0] = fmaf(ve0, ek, acc[0]);
          acc[4] = fmaf(ve0, f0k, acc[4]);
          if (k32 < 24) {
            float rb1k = ldv(rb1, e*24 + k32) * w;
            float f1k0 = ldv(f1, n*72 + k32);
            float f1k1 = ldv(f1, n*72 + 24 + k32);
            float f1k2 = ldv(f1, n*72 + 48 + k32);
            float rbek = rb1k * ek;
            acc[1] = fmaf(s1a0, rbek, acc[1]);
            acc[2] = fmaf(s1a1, rbek, acc[2]);
            acc[3] = fmaf(s1a2, rbek, acc[3]);
            acc[5] = fmaf(ve0, f1k0, acc[5]);
            acc[6] = fmaf(ve0, f1k1, acc[6]);
            acc[7] = fmaf(ve0, f1k2, acc[7]);
            float g3 = rb1k * f0k;
            acc[8]  = fmaf(g3, s1a0, acc[8]);
            acc[9]  = fmaf(g3, s1a1, acc[9]);
            acc[10] = fmaf(g3, s1a2, acc[10]);
            #pragma unroll
            for (int aa = 0; aa < 3; ++aa) {
              float sa = rb1k * ((aa==0)?s1a0:(aa==1)?s1a1:s1a2);
              acc[11+aa*3+0] = fmaf(sa, f1k0, acc[11+aa*3+0]);
              acc[11+aa*3+1] = fmaf(sa, f1k1, acc[11+aa*3+1]);
              acc[11+aa*3+2] = fmaf(sa, f1k2, acc[11+aa*3+2]);
            }
          }
        }
      }
    } else if (wv == 1) {
      for (int base = 0; base < nch; base += 8) {
        #pragma unroll
        for (int u = 0; u < 2; ++u) {
          int idx = base + 4*u + e4;
          float w = (idx < nch) ? 1.f : 0.f;
          int ic  = (idx < nch) ? idx : 0;
          int2 en = sel[ic];
          int e = en.x, n = en.y;
          float s0 = ldv(sh0, e);
          float s1a[3];
          #pragma unroll
          for (int m = 0; m < 3; ++m) s1a[m] = ldv(sh1, e*3+m);
          float s2a[5];
          #pragma unroll
          for (int m = 0; m < 5; ++m) s2a[m] = ldv(sh2, e*5+m);
          float rb0k = ldv(rb0, e*32 + k16) * w;
          float rb1k = ldv(rb1, e*24 + k16) * w;
          float rb2k = ldv(rb2, e*16 + k16) * w;
          float ek   = ldv(emb, n*32 + k16);
          float f2k[5];
          #pragma unroll
          for (int b = 0; b < 5; ++b) f2k[b] = ldv(f2, n*80 + b*16 + k16);
          float re = rb2k * ek;
          #pragma unroll
          for (int m = 0; m < 5; ++m) acc[m] = fmaf(s2a[m], re, acc[m]);
          float ve0 = s0 * rb0k;
          #pragma unroll
          for (int b = 0; b < 5; ++b) acc[5+b] = fmaf(ve0, f2k[b], acc[5+b]);
          #pragma unroll
          for (int aa = 0; aa < 3; ++aa) {
            float sa = rb1k * s1a[aa];
            #pragma unroll
            for (int b = 0; b < 5; ++b)
              acc[10+aa*5+b] = fmaf(sa, f2k[b], acc[10+aa*5+b]);
          }
        }
      }
    } else if (wv == 2) {
      for (int base = 0; base < nch; base += 8) {
        #pragma unroll
        for (int u = 0; u < 2; ++u) {
          int idx = base + 4*u + e4;
          float w = (idx < nch) ? 1.f : 0.f;
          int ic  = (idx < nch) ? idx : 0;
          int2 en = sel[ic];
          int e = en.x, n = en.y;
          float s2a[5];
          #pragma unroll
          for (int m = 0; m < 5; ++m) s2a[m] = ldv(sh2, e*5+m);
          float rb2k = ldv(rb2, e*16 + k16) * w;
          float f0k  = ldv(f0,  n*32 + k16);
          float f1k[3];
          #pragma unroll
          for (int b = 0; b < 3; ++b) f1k[b] = ldv(f1, n*72 + b*24 + k16);
          float g9 = rb2k * f0k;
          #pragma unroll
          for (int aa = 0; aa < 5; ++aa) acc[aa] = fmaf(g9, s2a[aa], acc[aa]);
          #pragma unroll
          for (int aa = 0; aa < 5; ++aa) {
            float sa = rb2k * s2a[aa];
            #pragma unroll
            for (int b = 0; b < 3; ++b)
              acc[5+aa*3+b] = fmaf(sa, f1k[b], acc[5+aa*3+b]);
          }
        }
      }
    } else {
      for (int base = 0; base < nch; base += 8) {
        #pragma unroll
        for (int u = 0; u < 2; ++u) {
          int idx = base + 4*u + e4;
          float w = (idx < nch) ? 1.f : 0.f;
          int ic  = (idx < nch) ? idx : 0;
          int2 en = sel[ic];
          int e = en.x, n = en.y;
          float s2a[5];
          #pragma unroll
          for (int m = 0; m < 5; ++m) s2a[m] = ldv(sh2, e*5+m);
          float rb2k = ldv(rb2, e*16 + k16) * w;
          float f2k[5];
          #pragma unroll
          for (int b = 0; b < 5; ++b) f2k[b] = ldv(f2, n*80 + b*16 + k16);
          #pragma unroll
          for (int aa = 0; aa < 5; ++aa) {
            float sa = rb2k * s2a[aa];
            #pragma unroll
            for (int b = 0; b < 5; ++b)
              acc[aa*5+b] = fmaf(sa, f2k[b], acc[aa*5+b]);
          }
        }
      }
    }
  }

  if (wv == 0) {
    #pragma unroll
    for (int i = 0; i < 20; ++i) acc[i] += __shfl_xor(acc[i], 32);
    const float* C000 = cgf + 0;
    const float* C011 = cgf + 1;
    const float* C101 = cgf + 35;
    const float* C110 = cgf + 44;
    const float* C111 = cgf + 53;
    const float* C112 = cgf + 80;
    float r[16];
    r[0] = C000[0] * acc[4];
    #pragma unroll
    for (int M = 0; M < 3; ++M) {
      float t = 0.f;
      #pragma unroll
      for (int b = 0; b < 3; ++b) t = fmaf(acc[5+b], C011[b*3+M], t);
      r[1+M] = t;
    }
    #pragma unroll
    for (int M = 0; M < 3; ++M) {
      float t = 0.f;
      #pragma unroll
      for (int aa = 0; aa < 3; ++aa) t = fmaf(acc[8+aa], C101[aa*3+M], t);
      r[4+M] = t;
    }
    {
      float t = 0.f;
      #pragma unroll
      for (int q = 0; q < 9; ++q) t = fmaf(acc[11+q], C110[q], t);
      r[7] = t;
    }
    #pragma unroll
    for (int M = 0; M < 3; ++M) {
      float t = 0.f;
      #pragma unroll
      for (int q = 0; q < 9; ++q) t = fmaf(acc[11+q], C111[q*3+M], t);
      r[8+M] = t;
    }
    #pragma unroll
    for (int M = 0; M < 5; ++M) {
      float t = 0.f;
      #pragma unroll
      for (int q = 0; q < 9; ++q) t = fmaf(acc[11+q], C112[q*5+M], t);
      r[11+M] = t;
    }
    acc[4] = r[0];
    #pragma unroll
    for (int M = 0; M < 3; ++M) acc[5+M]  = r[1+M];
    #pragma unroll
    for (int M = 0; M < 3; ++M) acc[8+M]  = r[4+M];
    acc[11] = r[7];
    #pragma unroll
    for (int M = 0; M < 3; ++M) acc[12+M] = r[8+M];
    #pragma unroll
    for (int M = 0; M < 5; ++M) acc[15+M] = r[11+M];
  } else if (wv == 1) {
    #pragma unroll
    for (int i = 0; i < 25; ++i) {
      acc[i] += __shfl_xor(acc[i], 16);
      acc[i] += __shfl_xor(acc[i], 32);
    }
    const float* C022 = cgf + 10;
    const float* C121 = cgf + 125;
    const float* C122 = cgf + 170;
    float r[13];
    #pragma unroll
    for (int M = 0; M < 5; ++M) {
      float t = 0.f;
      #pragma unroll
      for (int b = 0; b < 5; ++b) t = fmaf(acc[5+b], C022[b*5+M], t);
      r[M] = t;
    }
    #pragma unroll
    for (int M = 0; M < 3; ++M) {
      float t = 0.f;
      #pragma unroll
      for (int q = 0; q < 15; ++q) t = fmaf(acc[10+q], C121[q*3+M], t);
      r[5+M] = t;
    }
    #pragma unroll
    for (int M = 0; M < 5; ++M) {
      float t = 0.f;
      #pragma unroll
      for (int q = 0; q < 15; ++q) t = fmaf(acc[10+q], C122[q*5+M], t);
      r[8+M] = t;
    }
    #pragma unroll
    for (int M = 0; M < 5; ++M) acc[5+M]  = r[M];
    #pragma unroll
    for (int M = 0; M < 3; ++M) acc[10+M] = r[5+M];
    #pragma unroll
    for (int M = 0; M < 5; ++M) acc[13+M] = r[8+M];
  } else if (wv == 2) {
    #pragma unroll
    for (int i = 0; i < 20; ++i) {
      acc[i] += __shfl_xor(acc[i], 16);
      acc[i] += __shfl_xor(acc[i], 32);
    }
    const float* C202 = cgf + 245;
    const float* C211 = cgf + 270;
    const float* C212 = cgf + 315;
    float r[13];
    #pragma unroll
    for (int M = 0; M < 5; ++M) {
      float t = 0.f;
      #pragma unroll
      for (int aa = 0; aa < 5; ++aa) t = fmaf(acc[aa], C202[aa*5+M], t);
      r[M] = t;
    }
    #pragma unroll
    for (int M = 0; M < 3; ++M) {
      float t = 0.f;
      #pragma unroll
      for (int q = 0; q < 15; ++q) t = fmaf(acc[5+q], C211[q*3+M], t);
      r[5+M] = t;
    }
    #pragma unroll
    for (int M = 0; M < 5; ++M) {
      float t = 0.f;
      #pragma unroll
      for (int q = 0; q < 15; ++q) t = fmaf(acc[5+q], C212[q*5+M], t);
      r[8+M] = t;
    }
    #pragma unroll
    for (int M = 0; M < 5; ++M) acc[M]   = r[M];
    #pragma unroll
    for (int M = 0; M < 3; ++M) acc[5+M] = r[5+M];
    #pragma unroll
    for (int M = 0; M < 5; ++M) acc[8+M] = r[8+M];
  } else {
    #pragma unroll
    for (int i = 0; i < 25; ++i) {
      acc[i] += __shfl_xor(acc[i], 16);
      acc[i] += __shfl_xor(acc[i], 32);
    }
    const float* C220 = cgf + 390;
    const float* C221 = cgf + 415;
    const float* C222 = cgf + 490;
    float r[9];
    {
      float t = 0.f;
      #pragma unroll
      for (int q = 0; q < 25; ++q) t = fmaf(acc[q], C220[q], t);
      r[0] = t;
    }
    #pragma unroll
    for (int M = 0; M < 3; ++M) {
      float t = 0.f;
      #pragma unroll
      for (int q = 0; q < 25; ++q) t = fmaf(acc[q], C221[q*3+M], t);
      r[1+M] = t;
    }
    #pragma unroll
    for (int M = 0; M < 5; ++M) {
      float t = 0.f;
      #pragma unroll
      for (int q = 0; q < 25; ++q) t = fmaf(acc[q], C222[q*5+M], t);
      r[4+M] = t;
    }
    #pragma unroll
    for (int i = 0; i < 9; ++i) acc[i] = r[i];
  }

  if constexpr (MODE == 1) {
    if (wv == 0) {
      if (lane < 32) {
        stv(out, O0 + a*32 + k32, acc[0]);
        atomicAdd(&s1r[k32], acc[4]*acc[4]);
        if (k32 < 24) {
          #pragma unroll
          for (int m = 0; m < 3; ++m) stv(out, O1 + a*72 + m*24 + k32, acc[1+m]);
          atomicAdd(&s1r[32+k32], acc[11]*acc[11]);
          float q;
          q = acc[5]*acc[5]+acc[6]*acc[6]+acc[7]*acc[7];
          atomicAdd(&s1r[72+k32], q);
          q = acc[8]*acc[8]+acc[9]*acc[9]+acc[10]*acc[10];
          atomicAdd(&s1r[96+k32], q);
          q = acc[12]*acc[12]+acc[13]*acc[13]+acc[14]*acc[14];
          atomicAdd(&s1r[152+k32], q);
          q = acc[15]*acc[15]+acc[16]*acc[16]+acc[17]*acc[17]
            + acc[18]*acc[18]+acc[19]*acc[19];
          atomicAdd(&s1r[208+k32], q);
        }
      }
    } else if (wv == 1) {
      if (lane < 16) {
        #pragma unroll
        for (int m = 0; m < 5; ++m) stv(out, O2 + a*80 + m*16 + k16, acc[m]);
        float q;
        q = acc[5]*acc[5]+acc[6]*acc[6]+acc[7]*acc[7]+acc[8]*acc[8]+acc[9]*acc[9];
        atomicAdd(&s1r[192+k16], q);
        q = acc[10]*acc[10]+acc[11]*acc[11]+acc[12]*acc[12];
        atomicAdd(&s1r[120+k16], q);
        q = acc[13]*acc[13]+acc[14]*acc[14]+acc[15]*acc[15]
          + acc[16]*acc[16]+acc[17]*acc[17];
        atomicAdd(&s1r[264+k16], q);
      }
    } else if (wv == 2) {
      if (lane < 16) {
        float q;
        q = acc[0]*acc[0]+acc[1]*acc[1]+acc[2]*acc[2]+acc[3]*acc[3]+acc[4]*acc[4];
        atomicAdd(&s1r[232+k16], q);
        q = acc[5]*acc[5]+acc[6]*acc[6]+acc[7]*acc[7];
        atomicAdd(&s1r[136+k16], q);
        q = acc[8]*acc[8]+acc[9]*acc[9]+acc[10]*acc[10]
          + acc[11]*acc[11]+acc[12]*acc[12];
        atomicAdd(&s1r[280+k16], q);
      }
    } else {
      if (lane < 16) {
        atomicAdd(&s1r[56+k16], acc[0]*acc[0]);
        float q;
        q = acc[1]*acc[1]+acc[2]*acc[2]+acc[3]*acc[3];
        atomicAdd(&s1r[176+k16], q);
        q = acc[4]*acc[4]+acc[5]*acc[5]+acc[6]*acc[6]
          + acc[7]*acc[7]+acc[8]*acc[8];
        atomicAdd(&s1r[248+k16], q);
      }
    }
  }

  if constexpr (MODE == 2) {
    if (wv == 0) {
      if (lane < 32) {
        L[k32] = acc[4]*inv[k32];
        if (k32 < 24) {
          L[32+k32] = acc[11]*inv[32+k32];
          #pragma unroll
          for (int M = 0; M < 3; ++M) L[72+M*80+k32]     = acc[5+M]*inv[72+k32];
          #pragma unroll
          for (int M = 0; M < 3; ++M) L[72+M*80+24+k32]  = acc[8+M]*inv[96+k32];
          #pragma unroll
          for (int M = 0; M < 3; ++M) L[312+M*40+k32]    = acc[12+M]*inv[152+k32];
          #pragma unroll
          for (int M = 0; M < 5; ++M) L[432+M*72+16+k32] = acc[15+M]*inv[208+k32];
        }
      }
    } else if (wv == 1) {
      if (lane < 16) {
        #pragma unroll
        for (int M = 0; M < 5; ++M) L[432+M*72+k16]    = acc[5+M]*inv[192+k16];
        #pragma unroll
        for (int M = 0; M < 3; ++M) L[72+M*80+48+k16]  = acc[10+M]*inv[120+k16];
        #pragma unroll
        for (int M = 0; M < 5; ++M) L[792+M*32+k16]    = acc[13+M]*inv[264+k16];
      }
    } else if (wv == 2) {
      if (lane < 16) {
        #pragma unroll
        for (int M = 0; M < 5; ++M) L[432+M*72+40+k16] = acc[0+M]*inv[232+k16];
        #pragma unroll
        for (int M = 0; M < 3; ++M) L[72+M*80+64+k16]  = acc[5+M]*inv[136+k16];
        #pragma unroll
        for (int M = 0; M < 5; ++M) L[792+M*32+16+k16] = acc[8+M]*inv[280+k16];
      }
    } else {
      if (lane < 16) {
        L[56+k16] = acc[0]*inv[56+k16];
        #pragma unroll
        for (int M = 0; M < 3; ++M) L[312+M*40+24+k16] = acc[1+M]*inv[176+k16];
        #pragma unroll
        for (int M = 0; M < 5; ++M) L[432+M*72+56+k16] = acc[4+M]*inv[248+k16];
      }
    }
    __syncthreads();
    int t = threadIdx.x;
    float y2[5] = {0.f,0.f,0.f,0.f,0.f};
    for (int tau = t; tau < 336; tau += 256) {
      int ls = 0;
      while (tau >= c_cum[ls+1]) ++ls;
      int rem = tau - c_cum[ls];
      int kn = c_kout[ls], fin = c_fin[ls];
      int M = rem / kn, ko = rem - M*kn;
      const T* W = (const T*)lp.W[ls];
      float y = ldv((const T*)lp.B[ls], ko);
      const float* xv = &L[c_xb[ls] + M*fin];
      for (int f = 0; f < fin; ++f) y = fmaf(xv[f], ldv(W, f*kn+ko), y);
      stv(out, c_yoff[ls] + (a*c_Ms[ls] + M)*kn + ko, y);
      y2[ls] += y*y;
    }
    #pragma unroll
    for (int i = 0; i < 5; ++i) {
      y2[i] += __shfl_xor(y2[i], 1);  y2[i] += __shfl_xor(y2[i], 2);
      y2[i] += __shfl_xor(y2[i], 4);  y2[i] += __shfl_xor(y2[i], 8);
      y2[i] += __shfl_xor(y2[i], 16); y2[i] += __shfl_xor(y2[i], 32);
    }
    if (lane == 0) {
      #pragma unroll
      for (int i = 0; i < 5; ++i) red[wv][i] = y2[i];
    }
    __syncthreads();
    if (t == 0) {
      #pragma unroll
      for (int i = 0; i < 5; ++i)
        atomicAdd(&s2p[i*64 + ab], red[0][i]+red[1][i]+red[2][i]+red[3][i]);
    }
  }
}

extern "C" void kernel_launch(void* const* d_in, const int* in_sizes, int n_in,
                              void* d_out, int out_size, void* d_ws, size_t ws_size,
                              hipStream_t stream) {
  float* wsf = (float*)d_ws;
  int*   wsi = (int*)(wsf + SINTS);
  const int* centers   = (const int*)d_in[35];
  const int* neighbors = (const int*)d_in[36];
  bool big = ws_size >= (size_t)BIG_FLOATS * 4;

  // Host-side dtype detection (optimization only; kernels flag-gate if -1)
  int know = -1;
  if (in_sizes) {
    long long nb = (long long)in_sizes[0];         // rb0: 200000*32 elems
    if (nb == (long long)N_EDGES*32*2) know = 0;
    else if (nb == (long long)N_EDGES*32*4) know = 1;
  }
  if (know < 0) {
    long long ob = (long long)out_size;            // 5.2M output elems
    if (ob == (long long)OUT_ELEMS*2) know = 0;
    else if (ob == (long long)OUT_ELEMS*4) know = 1;
  }

  Ptrs15 cg;
  for (int i = 0; i < 15; ++i) cg.p[i] = d_in[10+i];
  LinP lp;
  lp.W[0] = d_in[25]; lp.B[0] = d_in[26];
  lp.W[1] = d_in[27]; lp.B[1] = d_in[28];
  lp.W[2] = d_in[29]; lp.B[2] = d_in[30];
  lp.W[3] = d_in[31]; lp.B[3] = d_in[32];
  lp.W[4] = d_in[33]; lp.B[4] = d_in[34];

  const int* flag = wsi + IFLAG;
  const int2* el2 = (const int2*)(wsi + IELIST);

  // ---- fused cooperative prep (fallback to legacy kernels on failure) ----
  {
    const unsigned short* rb0u = (const unsigned short*)d_in[0];
    const unsigned short* embu = (const unsigned short*)d_in[6];
    void* args[] = { (void*)&wsf, (void*)&wsi, (void*)&rb0u, (void*)&embu,
                     (void*)&centers, (void*)&neighbors, (void*)&cg, (void*)&know };
    hipError_t err = hipLaunchCooperativeKernel((void*)k_prep, dim3(256), dim3(256),
                                                args, 0, stream);
    if (err != hipSuccess) {
      (void)hipGetLastError();   // clear sticky error
      k_zero<<<154, 256, 0, stream>>>(wsf, wsi, rb0u, embu);
      k_hist<<<(N_EDGES+255)/256, 256, 0, stream>>>(centers, wsi+ICOUNT);
      k_scan<<<1, 1024, 0, stream>>>(wsi+ICOUNT, wsi+IOFFS);
      k_scatter2<<<(N_EDGES+255)/256, 256, 0, stream>>>(centers, neighbors, wsi+IOFFS,
                                                        wsi+ICURS, (int2*)(wsi+IELIST));
      if (know != 1) k_cg<bf16 ><<<3, 256, 0, stream>>>(cg, wsf, flag);
      if (know != 0) k_cg<float><<<3, 256, 0, stream>>>(cg, wsf, flag);
    }
  }

  if (big) {
    if (know != 1)
      k_role<bf16><<<N_ATOMS, 320, 0, stream>>>((const bf16*)d_in[0], (const bf16*)d_in[1],
          (const bf16*)d_in[2], (const bf16*)d_in[3], (const bf16*)d_in[4], (const bf16*)d_in[5],
          (const bf16*)d_in[6], (const bf16*)d_in[7], (const bf16*)d_in[8], (const bf16*)d_in[9],
          el2, wsi+IOFFS, wsf+SCG, wsf+SS1P, wsf+SXACC, (bf16*)d_out, flag);
    if (know != 0)
      k_role<float><<<N_ATOMS, 320, 0, stream>>>((const float*)d_in[0], (const float*)d_in[1],
          (const float*)d_in[2], (const float*)d_in[3], (const float*)d_in[4], (const float*)d_in[5],
          (const float*)d_in[6], (const float*)d_in[7], (const float*)d_in[8], (const float*)d_in[9],
          el2, wsi+IOFFS, wsf+SCG, wsf+SS1P, wsf+SXACC, (float*)d_out, flag);
    k_red1<<<296, 64, 0, stream>>>(wsf+SS1P, wsf+SINV);
    k_lin<<<N_ATOMS, 256, 0, stream>>>(wsf+SXACC, wsf+SINV, lp, d_out, wsf+SS2P,
                                       flag, know);
    k_scale<<<(3360000+255)/256, 256, 0, stream>>>(wsf+SS2P, d_out, flag, know);
  } else {
    // small-ws fallback: flag-gated dual chain (proven code, normally unused)
    k_main<bf16,1><<<N_ATOMS, 256, 0, stream>>>((const bf16*)d_in[0], (const bf16*)d_in[1],
        (const bf16*)d_in[2], (const bf16*)d_in[3], (const bf16*)d_in[4], (const bf16*)d_in[5],
        (const bf16*)d_in[6], (const bf16*)d_in[7], (const bf16*)d_in[8], (const bf16*)d_in[9],
        el2, wsi+IOFFS, wsf+SCG, wsf+SS1P, nullptr, nullptr, lp, (bf16*)d_out, flag);
    k_main<float,1><<<N_ATOMS, 256, 0, stream>>>((const float*)d_in[0], (const float*)d_in[1],
        (const float*)d_in[2], (const float*)d_in[3], (const float*)d_in[4], (const float*)d_in[5],
        (const float*)d_in[6], (const float*)d_in[7], (const float*)d_in[8], (const float*)d_in[9],
        el2, wsi+IOFFS, wsf+SCG, wsf+SS1P, nullptr, nullptr, lp, (float*)d_out, flag);
    k_red1<<<296, 64, 0, stream>>>(wsf+SS1P, wsf+SINV);
    k_main<bf16,2><<<N_ATOMS, 256, 0, stream>>>((const bf16*)d_in[0], (const bf16*)d_in[1],
        (const bf16*)d_in[2], (const bf16*)d_in[3], (const bf16*)d_in[4], (const bf16*)d_in[5],
        (const bf16*)d_in[6], (const bf16*)d_in[7], (const bf16*)d_in[8], (const bf16*)d_in[9],
        el2, wsi+IOFFS, wsf+SCG, nullptr, wsf+SINV, wsf+SS2P, lp, (bf16*)d_out, flag);
    k_main<float,2><<<N_ATOMS, 256, 0, stream>>>((const float*)d_in[0], (const float*)d_in[1],
        (const float*)d_in[2], (const float*)d_in[3], (const float*)d_in[4], (const float*)d_in[5],
        (const float*)d_in[6], (const float*)d_in[7], (const float*)d_in[8], (const float*)d_in[9],
        el2, wsi+IOFFS, wsf+SCG, nullptr, wsf+SINV, wsf+SS2P, lp, (float*)d_out, flag);
    k_scale<<<(3360000+255)/256, 256, 0, stream>>>(wsf+SS2P, d_out, flag, know);
  }
}

// Round 11
// 436.231 us; speedup vs baseline: 1.6546x; 1.6546x over previous
//
#include <hip/hip_runtime.h>
#include <hip/hip_bf16.h>

typedef __hip_bfloat16 bf16;

#define N_ATOMS 10000
#define N_EDGES 200000

// ======== float region of ws (float offsets) ========
#define SCG   0        // 615 cg coeffs f32
#define SINV  616      // 296 inv per channel (+pad)
#define SS1P  1024     // 64*296 partials [ab][ch]
#define SS2P  19968    // 5*64 partials
#define SWS2  20288    // 5 (+pad)
#define SINTS 20352    // int region starts here (float idx)
// ======== int region (offsets in ints, relative to SINTS) ========
#define IFLAG  0
#define ICOUNT 16      // 10000
#define IOFFS  10016   // 10001 (+pad)
#define ICURS  20032   // 10000
#define IELIST 30032   // 400000 ints (int2 records)
#define INTS_END 430032
#define SXACC (SINTS + INTS_END)
#define BIG_FLOATS (SXACC + 952*N_ATOMS)      // ~39.9 MB

// ---- d_out element offsets ----
#define O0 0
#define O1 320000
#define O2 1040000
#define OY 1840000
#define OUT_ELEMS 5200000

__device__ __forceinline__ float b2f(bf16 x){ return __bfloat162float(x); }
__device__ __forceinline__ bf16  f2b(float x){ return __float2bfloat16(x); }

__device__ __forceinline__ float ldv(const float* p, int i){ return p[i]; }
__device__ __forceinline__ float ldv(const bf16*  p, int i){ return b2f(p[i]); }
__device__ __forceinline__ void  stv(float* p, int i, float v){ p[i] = v; }
__device__ __forceinline__ void  stv(bf16*  p, int i, float v){ p[i] = f2b(v); }

template<typename T> __device__ __forceinline__ int dtid();
template<> __device__ __forceinline__ int dtid<bf16>(){ return 0; }
template<> __device__ __forceinline__ int dtid<float>(){ return 1; }

struct Ptrs15 { const void* p[15]; };
struct LinP   { const void* W[5]; const void* B[5]; };

__constant__ int c_cg_sizes[15] = {1,9,25,9,9,27,45,45,75,25,45,75,25,75,125};
__constant__ int c_fin[5]   = {72,80,40,72,32};
__constant__ int c_kout[5]  = {32,24,24,16,16};
__constant__ int c_yoff[5]  = {OY+0, OY+320000, OY+1040000, OY+1760000, OY+2560000};
__constant__ int c_numel[5] = {320000,720000,720000,800000,800000};
__constant__ int c_cum[6]   = {0,32,104,176,256,336};
__constant__ int c_xb[5]    = {0,72,312,432,792};
__constant__ int c_Ms[5]    = {1,3,3,5,5};

// ---------------- zero + dtype probe (+cg convert when dtype known) ---------
// NOTE (round-10 lesson): NEVER use cooperative grid.sync on this platform --
// one grid.sync measured ~70us (k_prep: 283us @ 0.09% VALUBusy). Kernel launch
// boundaries (~2us) ARE the cheap grid-wide sync primitive here.
__global__ void k_zero(float* wsf, int* wsi,
                       const unsigned short* rb0u, const unsigned short* embu,
                       Ptrs15 cg, int know) {
  if (blockIdx.x == 0 && threadIdx.x < 64) {
    int lane = threadIdx.x;
    int bad = 0;
    for (int i = lane; i < 256; i += 64) {
      unsigned u1 = ((unsigned)rb0u[2*i]) << 16;
      unsigned u2 = ((unsigned)embu[2*i]) << 16;
      float v1 = __uint_as_float(u1);
      float v2 = __uint_as_float(u2);
      if (!(fabsf(v1) < 1e9f) || !(fabsf(v2) < 1e9f)) bad = 1;
    }
    unsigned long long any = __ballot(bad);
    if (lane == 0) wsi[IFLAG] = (any != 0ULL) ? 1 : 0;   // 1 = fp32, 0 = bf16
  }
  int i = blockIdx.x*blockDim.x + threadIdx.x;
  if (i < N_ATOMS) wsi[ICOUNT + i] = 0;
  int j = i - N_ATOMS;
  if (j >= 0 && j < N_ATOMS) wsi[ICURS + j] = 0;
  j -= N_ATOMS;
  if (j >= 0 && j < 18944) wsf[SS1P + j] = 0.f;
  j -= 18944;
  if (j >= 0 && j < 325) wsf[SS2P + j] = 0.f;
  j -= 325;
  if (j >= 0 && j < 615 && know >= 0) {
    int s = 0, off = j;
    while (off >= c_cg_sizes[s]) { off -= c_cg_sizes[s]; ++s; }
    wsf[SCG + j] = (know == 0) ? b2f(((const bf16*)cg.p[s])[off])
                               : ((const float*)cg.p[s])[off];
  }
}

// CG pre-convert (fallback when host couldn't determine dtype)
template<typename T>
__global__ void k_cg(Ptrs15 cg, float* wsf, const int* flag) {
  if (flag[0] != dtid<T>()) return;
  int i = blockIdx.x*blockDim.x + threadIdx.x;
  if (i >= 615) return;
  int s = 0, off = i;
  while (off >= c_cg_sizes[s]) { off -= c_cg_sizes[s]; ++s; }
  wsf[SCG + i] = ldv((const T*)cg.p[s], off);
}

__global__ void k_hist(const int* __restrict__ centers, int* __restrict__ counts) {
  int e = blockIdx.x*blockDim.x + threadIdx.x;
  if (e < N_EDGES) atomicAdd(&counts[centers[e]], 1);
}

__global__ void k_scan(const int* __restrict__ counts, int* __restrict__ offs) {
  __shared__ int part[1024];
  int t = threadIdx.x;
  int base = t*10;
  int s = 0;
  for (int i = 0; i < 10; ++i) { int idx = base+i; if (idx < N_ATOMS) s += counts[idx]; }
  part[t] = s;
  __syncthreads();
  for (int d = 1; d < 1024; d <<= 1) {
    int v = part[t];
    int add = (t >= d) ? part[t-d] : 0;
    __syncthreads();
    part[t] = v + add;
    __syncthreads();
  }
  int run = (t == 0) ? 0 : part[t-1];
  for (int i = 0; i < 10; ++i) {
    int idx = base+i;
    if (idx < N_ATOMS) { offs[idx] = run; run += counts[idx]; }
  }
  if (t == 1023) offs[N_ATOMS] = part[1023];
}

__global__ void k_scatter2(const int* __restrict__ centers, const int* __restrict__ neighbors,
                           const int* __restrict__ offs, int* __restrict__ cursors,
                           int2* __restrict__ elist2) {
  int e = blockIdx.x*blockDim.x + threadIdx.x;
  if (e < N_EDGES) {
    int c = centers[e];
    int p = atomicAdd(&cursors[c], 1);
    elist2[offs[c] + p] = make_int2(e, neighbors[e]);
  }
}

// ---------------- role kernel (big path) -- R9 shape, proven best -----------
// ONE atom per 320-thread block (5 role-waves co-located: L1 dedupe of edge
// rows, write-combining of the xg record). 32-VGPR template body. No barriers,
// no LDS. XCD swizzle (bijective: 10000 = 8*1250).
// role 0: d0,d1 + x000,x011      role 1: x110,x101,x111,x112
// role 2: d2 + x022,x121,x122    role 3: x202,x211,x212    role 4: x220,x221,x222
template<typename T>
__global__ __launch_bounds__(320, 8) void k_role(
    const T* __restrict__ rb0, const T* __restrict__ rb1, const T* __restrict__ rb2,
    const T* __restrict__ sh0, const T* __restrict__ sh1, const T* __restrict__ sh2,
    const T* __restrict__ emb, const T* __restrict__ f0, const T* __restrict__ f1,
    const T* __restrict__ f2, const int2* __restrict__ el2,
    const int* __restrict__ offs, const float* __restrict__ cgf,
    float* __restrict__ s1p, float* __restrict__ xout, T* __restrict__ out,
    const int* __restrict__ flag)
{
  if (flag[0] != dtid<T>()) return;
  int lane = threadIdx.x & 63;
  int role = threadIdx.x >> 6;                 // 0..4
  int xcd = blockIdx.x & 7;
  int al  = blockIdx.x >> 3;                   // 0..1249
  int a = al * 8 + xcd;                        // bijective over 10000
  int beg = offs[a];
  int cnt = offs[a+1] - beg;
  const int2* eb = el2 + beg;
  int ab = a & 63;
  int k32 = lane & 31, e2 = lane >> 5;
  int k16 = lane & 15, e4 = lane >> 4;
  float* xg = xout + a*952;
  float* s1r = s1p + ab*296;

  if (role == 0) {
    float acc[8];
    #pragma unroll
    for (int i = 0; i < 8; ++i) acc[i] = 0.f;
    for (int base = 0; base < cnt; base += 4) {
      #pragma unroll
      for (int u = 0; u < 2; ++u) {
        int idx = base + 2*u + e2;
        float w = (idx < cnt) ? 1.f : 0.f;
        int ic  = (idx < cnt) ? idx : 0;
        int2 en = eb[ic];
        int e = en.x, n = en.y;
        float s0 = ldv(sh0, e);
        float s1a0 = ldv(sh1, e*3+0), s1a1 = ldv(sh1, e*3+1), s1a2 = ldv(sh1, e*3+2);
        float rb0k = ldv(rb0, e*32 + k32) * w;
        float ek   = ldv(emb, n*32 + k32);
        float f0k  = ldv(f0,  n*32 + k32);
        float ve0 = s0 * rb0k;
        acc[0] = fmaf(ve0, ek, acc[0]);
        acc[4] = fmaf(ve0, f0k, acc[4]);
        if (k32 < 24) {
          float rb1k = ldv(rb1, e*24 + k32) * w;
          float rbek = rb1k * ek;
          acc[1] = fmaf(s1a0, rbek, acc[1]);
          acc[2] = fmaf(s1a1, rbek, acc[2]);
          acc[3] = fmaf(s1a2, rbek, acc[3]);
          float f1k0 = ldv(f1, n*72 + k32);
          float f1k1 = ldv(f1, n*72 + 24 + k32);
          float f1k2 = ldv(f1, n*72 + 48 + k32);
          acc[5] = fmaf(ve0, f1k0, acc[5]);
          acc[6] = fmaf(ve0, f1k1, acc[6]);
          acc[7] = fmaf(ve0, f1k2, acc[7]);
        }
      }
    }
    #pragma unroll
    for (int i = 0; i < 8; ++i) acc[i] += __shfl_xor(acc[i], 32);
    const float* C011 = cgf + 1;
    float x000 = cgf[0] * acc[4];
    float x011[3];
    #pragma unroll
    for (int M = 0; M < 3; ++M) {
      float t = 0.f;
      #pragma unroll
      for (int b = 0; b < 3; ++b) t = fmaf(acc[5+b], C011[b*3+M], t);
      x011[M] = t;
    }
    if (lane < 32) {
      stv(out, O0 + a*32 + k32, acc[0]);
      xg[k32] = x000;
      atomicAdd(&s1r[k32], x000*x000);
      if (k32 < 24) {
        #pragma unroll
        for (int m = 0; m < 3; ++m) stv(out, O1 + a*72 + m*24 + k32, acc[1+m]);
        #pragma unroll
        for (int M = 0; M < 3; ++M) xg[72+M*80+k32] = x011[M];
        atomicAdd(&s1r[72+k32], x011[0]*x011[0]+x011[1]*x011[1]+x011[2]*x011[2]);
      }
    }
  } else if (role == 1) {
    float acc[12];
    #pragma unroll
    for (int i = 0; i < 12; ++i) acc[i] = 0.f;
    int k24 = (k32 < 24) ? k32 : 23;
    float m24 = (k32 < 24) ? 1.f : 0.f;
    for (int base = 0; base < cnt; base += 4) {
      #pragma unroll
      for (int u = 0; u < 2; ++u) {
        int idx = base + 2*u + e2;
        float w = ((idx < cnt) ? 1.f : 0.f) * m24;
        int ic  = (idx < cnt) ? idx : 0;
        int2 en = eb[ic];
        int e = en.x, n = en.y;
        float s1a0 = ldv(sh1, e*3+0), s1a1 = ldv(sh1, e*3+1), s1a2 = ldv(sh1, e*3+2);
        float rb1k = ldv(rb1, e*24 + k24) * w;
        float f0k  = ldv(f0,  n*32 + k24);
        float f1k0 = ldv(f1, n*72 + k24);
        float f1k1 = ldv(f1, n*72 + 24 + k24);
        float f1k2 = ldv(f1, n*72 + 48 + k24);
        float g3 = rb1k * f0k;
        acc[0] = fmaf(g3, s1a0, acc[0]);
        acc[1] = fmaf(g3, s1a1, acc[1]);
        acc[2] = fmaf(g3, s1a2, acc[2]);
        float sa;
        sa = rb1k * s1a0;
        acc[3] = fmaf(sa, f1k0, acc[3]); acc[4] = fmaf(sa, f1k1, acc[4]); acc[5] = fmaf(sa, f1k2, acc[5]);
        sa = rb1k * s1a1;
        acc[6] = fmaf(sa, f1k0, acc[6]); acc[7] = fmaf(sa, f1k1, acc[7]); acc[8] = fmaf(sa, f1k2, acc[8]);
        sa = rb1k * s1a2;
        acc[9] = fmaf(sa, f1k0, acc[9]); acc[10] = fmaf(sa, f1k1, acc[10]); acc[11] = fmaf(sa, f1k2, acc[11]);
      }
    }
    #pragma unroll
    for (int i = 0; i < 12; ++i) acc[i] += __shfl_xor(acc[i], 32);
    const float* C101 = cgf + 35;
    const float* C110 = cgf + 44;
    const float* C111 = cgf + 53;
    const float* C112 = cgf + 80;
    float x101[3], x111[3], x112[5], x110;
    #pragma unroll
    for (int M = 0; M < 3; ++M) {
      float t = 0.f;
      #pragma unroll
      for (int aa = 0; aa < 3; ++aa) t = fmaf(acc[aa], C101[aa*3+M], t);
      x101[M] = t;
    }
    {
      float t = 0.f;
      #pragma unroll
      for (int q = 0; q < 9; ++q) t = fmaf(acc[3+q], C110[q], t);
      x110 = t;
    }
    #pragma unroll
    for (int M = 0; M < 3; ++M) {
      float t = 0.f;
      #pragma unroll
      for (int q = 0; q < 9; ++q) t = fmaf(acc[3+q], C111[q*3+M], t);
      x111[M] = t;
    }
    #pragma unroll
    for (int M = 0; M < 5; ++M) {
      float t = 0.f;
      #pragma unroll
      for (int q = 0; q < 9; ++q) t = fmaf(acc[3+q], C112[q*5+M], t);
      x112[M] = t;
    }
    if (lane < 24) {
      xg[32+k32] = x110;
      #pragma unroll
      for (int M = 0; M < 3; ++M) xg[72+M*80+24+k32] = x101[M];
      #pragma unroll
      for (int M = 0; M < 3; ++M) xg[312+M*40+k32]   = x111[M];
      #pragma unroll
      for (int M = 0; M < 5; ++M) xg[432+M*72+16+k32] = x112[M];
      atomicAdd(&s1r[32+k32], x110*x110);
      atomicAdd(&s1r[96+k32], x101[0]*x101[0]+x101[1]*x101[1]+x101[2]*x101[2]);
      atomicAdd(&s1r[152+k32], x111[0]*x111[0]+x111[1]*x111[1]+x111[2]*x111[2]);
      atomicAdd(&s1r[208+k32], x112[0]*x112[0]+x112[1]*x112[1]+x112[2]*x112[2]
                              + x112[3]*x112[3]+x112[4]*x112[4]);
    }
  } else if (role == 2) {
    float acc[25];
    #pragma unroll
    for (int i = 0; i < 25; ++i) acc[i] = 0.f;
    for (int base = 0; base < cnt; base += 8) {
      #pragma unroll
      for (int u = 0; u < 2; ++u) {
        int idx = base + 4*u + e4;
        float w = (idx < cnt) ? 1.f : 0.f;
        int ic  = (idx < cnt) ? idx : 0;
        int2 en = eb[ic];
        int e = en.x, n = en.y;
        float s0 = ldv(sh0, e);
        float s1a[3];
        #pragma unroll
        for (int m = 0; m < 3; ++m) s1a[m] = ldv(sh1, e*3+m);
        float s2a[5];
        #pragma unroll
        for (int m = 0; m < 5; ++m) s2a[m] = ldv(sh2, e*5+m);
        float rb0k = ldv(rb0, e*32 + k16) * w;
        float rb1k = ldv(rb1, e*24 + k16) * w;
        float rb2k = ldv(rb2, e*16 + k16) * w;
        float ek   = ldv(emb, n*32 + k16);
        float f2k[5];
        #pragma unroll
        for (int b = 0; b < 5; ++b) f2k[b] = ldv(f2, n*80 + b*16 + k16);
        float re = rb2k * ek;
        #pragma unroll
        for (int m = 0; m < 5; ++m) acc[m] = fmaf(s2a[m], re, acc[m]);
        float ve0 = s0 * rb0k;
        #pragma unroll
        for (int b = 0; b < 5; ++b) acc[5+b] = fmaf(ve0, f2k[b], acc[5+b]);
        #pragma unroll
        for (int aa = 0; aa < 3; ++aa) {
          float sa = rb1k * s1a[aa];
          #pragma unroll
          for (int b = 0; b < 5; ++b)
            acc[10+aa*5+b] = fmaf(sa, f2k[b], acc[10+aa*5+b]);
        }
      }
    }
    #pragma unroll
    for (int i = 0; i < 25; ++i) {
      acc[i] += __shfl_xor(acc[i], 16);
      acc[i] += __shfl_xor(acc[i], 32);
    }
    const float* C022 = cgf + 10;
    const float* C121 = cgf + 125;
    const float* C122 = cgf + 170;
    float x022[5], x121[3], x122[5];
    #pragma unroll
    for (int M = 0; M < 5; ++M) {
      float t = 0.f;
      #pragma unroll
      for (int b = 0; b < 5; ++b) t = fmaf(acc[5+b], C022[b*5+M], t);
      x022[M] = t;
    }
    #pragma unroll
    for (int M = 0; M < 3; ++M) {
      float t = 0.f;
      #pragma unroll
      for (int q = 0; q < 15; ++q) t = fmaf(acc[10+q], C121[q*3+M], t);
      x121[M] = t;
    }
    #pragma unroll
    for (int M = 0; M < 5; ++M) {
      float t = 0.f;
      #pragma unroll
      for (int q = 0; q < 15; ++q) t = fmaf(acc[10+q], C122[q*5+M], t);
      x122[M] = t;
    }
    if (lane < 16) {
      #pragma unroll
      for (int m = 0; m < 5; ++m) stv(out, O2 + a*80 + m*16 + k16, acc[m]);
      #pragma unroll
      for (int M = 0; M < 5; ++M) xg[432+M*72+k16]   = x022[M];
      #pragma unroll
      for (int M = 0; M < 3; ++M) xg[72+M*80+48+k16] = x121[M];
      #pragma unroll
      for (int M = 0; M < 5; ++M) xg[792+M*32+k16]   = x122[M];
      atomicAdd(&s1r[192+k16], x022[0]*x022[0]+x022[1]*x022[1]+x022[2]*x022[2]
                              + x022[3]*x022[3]+x022[4]*x022[4]);
      atomicAdd(&s1r[120+k16], x121[0]*x121[0]+x121[1]*x121[1]+x121[2]*x121[2]);
      atomicAdd(&s1r[264+k16], x122[0]*x122[0]+x122[1]*x122[1]+x122[2]*x122[2]
                              + x122[3]*x122[3]+x122[4]*x122[4]);
    }
  } else if (role == 3) {
    float acc[20];
    #pragma unroll
    for (int i = 0; i < 20; ++i) acc[i] = 0.f;
    for (int base = 0; base < cnt; base += 8) {
      #pragma unroll
      for (int u = 0; u < 2; ++u) {
        int idx = base + 4*u + e4;
        float w = (idx < cnt) ? 1.f : 0.f;
        int ic  = (idx < cnt) ? idx : 0;
        int2 en = eb[ic];
        int e = en.x, n = en.y;
        float s2a[5];
        #pragma unroll
        for (int m = 0; m < 5; ++m) s2a[m] = ldv(sh2, e*5+m);
        float rb2k = ldv(rb2, e*16 + k16) * w;
        float f0k  = ldv(f0,  n*32 + k16);
        float f1k[3];
        #pragma unroll
        for (int b = 0; b < 3; ++b) f1k[b] = ldv(f1, n*72 + b*24 + k16);
        float g9 = rb2k * f0k;
        #pragma unroll
        for (int aa = 0; aa < 5; ++aa) acc[aa] = fmaf(g9, s2a[aa], acc[aa]);
        #pragma unroll
        for (int aa = 0; aa < 5; ++aa) {
          float sa = rb2k * s2a[aa];
          #pragma unroll
          for (int b = 0; b < 3; ++b)
            acc[5+aa*3+b] = fmaf(sa, f1k[b], acc[5+aa*3+b]);
        }
      }
    }
    #pragma unroll
    for (int i = 0; i < 20; ++i) {
      acc[i] += __shfl_xor(acc[i], 16);
      acc[i] += __shfl_xor(acc[i], 32);
    }
    const float* C202 = cgf + 245;
    const float* C211 = cgf + 270;
    const float* C212 = cgf + 315;
    float x202[5], x211[3], x212[5];
    #pragma unroll
    for (int M = 0; M < 5; ++M) {
      float t = 0.f;
      #pragma unroll
      for (int aa = 0; aa < 5; ++aa) t = fmaf(acc[aa], C202[aa*5+M], t);
      x202[M] = t;
    }
    #pragma unroll
    for (int M = 0; M < 3; ++M) {
      float t = 0.f;
      #pragma unroll
      for (int q = 0; q < 15; ++q) t = fmaf(acc[5+q], C211[q*3+M], t);
      x211[M] = t;
    }
    #pragma unroll
    for (int M = 0; M < 5; ++M) {
      float t = 0.f;
      #pragma unroll
      for (int q = 0; q < 15; ++q) t = fmaf(acc[5+q], C212[q*5+M], t);
      x212[M] = t;
    }
    if (lane < 16) {
      #pragma unroll
      for (int M = 0; M < 5; ++M) xg[432+M*72+40+k16] = x202[M];
      #pragma unroll
      for (int M = 0; M < 3; ++M) xg[72+M*80+64+k16]  = x211[M];
      #pragma unroll
      for (int M = 0; M < 5; ++M) xg[792+M*32+16+k16] = x212[M];
      atomicAdd(&s1r[232+k16], x202[0]*x202[0]+x202[1]*x202[1]+x202[2]*x202[2]
                              + x202[3]*x202[3]+x202[4]*x202[4]);
      atomicAdd(&s1r[136+k16], x211[0]*x211[0]+x211[1]*x211[1]+x211[2]*x211[2]);
      atomicAdd(&s1r[280+k16], x212[0]*x212[0]+x212[1]*x212[1]+x212[2]*x212[2]
                              + x212[3]*x212[3]+x212[4]*x212[4]);
    }
  } else {
    float acc[25];
    #pragma unroll
    for (int i = 0; i < 25; ++i) acc[i] = 0.f;
    for (int base = 0; base < cnt; base += 8) {
      #pragma unroll
      for (int u = 0; u < 2; ++u) {
        int idx = base + 4*u + e4;
        float w = (idx < cnt) ? 1.f : 0.f;
        int ic  = (idx < cnt) ? idx : 0;
        int2 en = eb[ic];
        int e = en.x, n = en.y;
        float s2a[5];
        #pragma unroll
        for (int m = 0; m < 5; ++m) s2a[m] = ldv(sh2, e*5+m);
        float rb2k = ldv(rb2, e*16 + k16) * w;
        float f2k[5];
        #pragma unroll
        for (int b = 0; b < 5; ++b) f2k[b] = ldv(f2, n*80 + b*16 + k16);
        #pragma unroll
        for (int aa = 0; aa < 5; ++aa) {
          float sa = rb2k * s2a[aa];
          #pragma unroll
          for (int b = 0; b < 5; ++b)
            acc[aa*5+b] = fmaf(sa, f2k[b], acc[aa*5+b]);
        }
      }
    }
    #pragma unroll
    for (int i = 0; i < 25; ++i) {
      acc[i] += __shfl_xor(acc[i], 16);
      acc[i] += __shfl_xor(acc[i], 32);
    }
    const float* C220 = cgf + 390;
    const float* C221 = cgf + 415;
    const float* C222 = cgf + 490;
    float x220, x221[3], x222[5];
    {
      float t = 0.f;
      #pragma unroll
      for (int q = 0; q < 25; ++q) t = fmaf(acc[q], C220[q], t);
      x220 = t;
    }
    #pragma unroll
    for (int M = 0; M < 3; ++M) {
      float t = 0.f;
      #pragma unroll
      for (int q = 0; q < 25; ++q) t = fmaf(acc[q], C221[q*3+M], t);
      x221[M] = t;
    }
    #pragma unroll
    for (int M = 0; M < 5; ++M) {
      float t = 0.f;
      #pragma unroll
      for (int q = 0; q < 25; ++q) t = fmaf(acc[q], C222[q*5+M], t);
      x222[M] = t;
    }
    if (lane < 16) {
      xg[56+k16] = x220;
      #pragma unroll
      for (int M = 0; M < 3; ++M) xg[312+M*40+24+k16] = x221[M];
      #pragma unroll
      for (int M = 0; M < 5; ++M) xg[432+M*72+56+k16] = x222[M];
      atomicAdd(&s1r[56+k16], x220*x220);
      atomicAdd(&s1r[176+k16], x221[0]*x221[0]+x221[1]*x221[1]+x221[2]*x221[2]);
      atomicAdd(&s1r[248+k16], x222[0]*x222[0]+x222[1]*x222[1]+x222[2]*x222[2]
                              + x222[3]*x222[3]+x222[4]*x222[4]);
    }
  }
}

// ---------------- big path: normalize + linear from stored x ----------------
template<typename T>
__device__ __forceinline__ void lin_body(
    const float* __restrict__ xg, const float* __restrict__ inv,
    LinP lp, T* __restrict__ out, float* __restrict__ s2p)
{
  int a = blockIdx.x;
  int t = threadIdx.x;
  __shared__ float L[952];
  for (int i = t; i < 952; i += 256) {
    int ch;
    if      (i < 72)  ch = i;
    else if (i < 312) ch = 72  + (i-72)  % 80;
    else if (i < 432) ch = 152 + (i-312) % 40;
    else if (i < 792) ch = 192 + (i-432) % 72;
    else              ch = 264 + (i-792) % 32;
    L[i] = xg[a*952 + i] * inv[ch];
  }
  __syncthreads();
  float y2[5] = {0.f,0.f,0.f,0.f,0.f};
  for (int tau = t; tau < 336; tau += 256) {
    int ls = 0;
    while (tau >= c_cum[ls+1]) ++ls;
    int rem = tau - c_cum[ls];
    int kn = c_kout[ls], fin = c_fin[ls];
    int M = rem / kn, ko = rem - M*kn;
    const T* W = (const T*)lp.W[ls];
    float y = ldv((const T*)lp.B[ls], ko);
    const float* xv = &L[c_xb[ls] + M*fin];
    for (int f = 0; f < fin; ++f) y = fmaf(xv[f], ldv(W, f*kn+ko), y);
    stv(out, c_yoff[ls] + (a*c_Ms[ls] + M)*kn + ko, y);
    y2[ls] += y*y;
  }
  __shared__ float red[4][5];
  #pragma unroll
  for (int i = 0; i < 5; ++i) {
    y2[i] += __shfl_xor(y2[i], 1);  y2[i] += __shfl_xor(y2[i], 2);
    y2[i] += __shfl_xor(y2[i], 4);  y2[i] += __shfl_xor(y2[i], 8);
    y2[i] += __shfl_xor(y2[i], 16); y2[i] += __shfl_xor(y2[i], 32);
  }
  if ((t & 63) == 0) {
    #pragma unroll
    for (int i = 0; i < 5; ++i) red[t>>6][i] = y2[i];
  }
  __syncthreads();
  if (t == 0) {
    #pragma unroll
    for (int i = 0; i < 5; ++i)
      atomicAdd(&s2p[i*64 + (a & 63)], red[0][i]+red[1][i]+red[2][i]+red[3][i]);
  }
}

__global__ __launch_bounds__(256) void k_lin(
    const float* __restrict__ xg, const float* __restrict__ inv,
    LinP lp, void* outv, float* __restrict__ s2p,
    const int* __restrict__ flag, int know)
{
  int dt = (know >= 0) ? know : flag[0];
  if (dt == 0) lin_body<bf16>(xg, inv, lp, (bf16*)outv, s2p);
  else         lin_body<float>(xg, inv, lp, (float*)outv, s2p);
}

// ---------------- reducer for s1p ----------------
__global__ void k_red1(const float* __restrict__ s1p, float* __restrict__ inv) {
  int ch = blockIdx.x, lane = threadIdx.x;
  float v = s1p[lane*296 + ch];
  v += __shfl_xor(v, 1);  v += __shfl_xor(v, 2);  v += __shfl_xor(v, 4);
  v += __shfl_xor(v, 8);  v += __shfl_xor(v, 16); v += __shfl_xor(v, 32);
  if (lane == 0) {
    float rows = (ch < 72) ? 10000.f : (ch < 192) ? 30000.f : 50000.f;
    inv[ch] = rsqrtf(v/rows + 1e-12f);
  }
}

// ---------------- final global RMS scale (fused s2p reduction) --------------
__global__ __launch_bounds__(256) void k_scale(
    const float* __restrict__ s2p, void* outv,
    const int* __restrict__ flag, int know)
{
  __shared__ float ssum[5];
  int t = threadIdx.x;
  if (t < 64) {
    #pragma unroll
    for (int i = 0; i < 5; ++i) {
      float x = s2p[i*64 + t];
      x += __shfl_xor(x, 1);  x += __shfl_xor(x, 2);  x += __shfl_xor(x, 4);
      x += __shfl_xor(x, 8);  x += __shfl_xor(x, 16); x += __shfl_xor(x, 32);
      if (t == 0) ssum[i] = x;
    }
  }
  __syncthreads();
  int dt = (know >= 0) ? know : flag[0];
  int i = blockIdx.x*blockDim.x + t;
  if (i >= 3360000) return;
  int ls = (i < 320000) ? 0 : (i < 1040000) ? 1 : (i < 1760000) ? 2 : (i < 2560000) ? 3 : 4;
  float scale = rsqrtf(ssum[ls] / (float)c_numel[ls] + 1e-12f);
  if (dt == 0) { bf16* o = (bf16*)outv;  stv(o, OY+i, ldv((const bf16*)o,  OY+i) * scale); }
  else         { float* o = (float*)outv; stv(o, OY+i, ldv((const float*)o, OY+i) * scale); }
}

// ---------------- monolithic kernel (small-ws fallback only) ---------------
template<typename T, int MODE>
__global__ __launch_bounds__(256) void k_main(
    const T* __restrict__ rb0, const T* __restrict__ rb1, const T* __restrict__ rb2,
    const T* __restrict__ sh0, const T* __restrict__ sh1, const T* __restrict__ sh2,
    const T* __restrict__ emb, const T* __restrict__ f0, const T* __restrict__ f1,
    const T* __restrict__ f2, const int2* __restrict__ el2,
    const int* __restrict__ offs, const float* __restrict__ cgf,
    float* __restrict__ s1p, const float* __restrict__ inv,
    float* __restrict__ s2p, LinP lp, T* __restrict__ out,
    const int* __restrict__ flag)
{
  if (flag[0] != dtid<T>()) return;
  int lane = threadIdx.x & 63;
  int wv   = threadIdx.x >> 6;
  int tix  = threadIdx.x;
  int a = blockIdx.x;
  int beg = offs[a];
  int cnt = offs[a+1] - beg;
  int k32 = lane & 31, e2 = lane >> 5;
  int k16 = lane & 15, e4 = lane >> 4;
  int ab = a & 63;
  float* s1r = s1p + ab*296;

  __shared__ int2 sel[256];
  __shared__ __align__(16) float L[952];
  __shared__ float red[4][5];

  float acc[25];
  #pragma unroll
  for (int i = 0; i < 25; ++i) acc[i] = 0.f;

  for (int cbase = 0; cbase < cnt; cbase += 256) {
    int nch = cnt - cbase; if (nch > 256) nch = 256;
    __syncthreads();
    if (tix < nch) sel[tix] = el2[beg + cbase + tix];
    __syncthreads();

    if (wv == 0) {
      for (int base = 0; base < nch; base += 4) {
        #pragma unroll
        for (int u = 0; u < 2; ++u) {
          int idx = base + 2*u + e2;
          float w = (idx < nch) ? 1.f : 0.f;
          int ic  = (idx < nch) ? idx : 0;
          int2 en = sel[ic];
          int e = en.x, n = en.y;
          float s0 = ldv(sh0, e);
          float s1a0 = ldv(sh1, e*3+0), s1a1 = ldv(sh1, e*3+1), s1a2 = ldv(sh1, e*3+2);
          float rb0k = ldv(rb0, e*32 + k32) * w;
          float ek   = ldv(emb, n*32 + k32);
          float f0k  = ldv(f0,  n*32 + k32);
          float ve0 = s0 * rb0k;
          acc[0] = fmaf(ve0, ek, acc[0]);
          acc[4] = fmaf(ve0, f0k, acc[4]);
          if (k32 < 24) {
            float rb1k = ldv(rb1, e*24 + k32) * w;
            float f1k0 = ldv(f1, n*72 + k32);
            float f1k1 = ldv(f1, n*72 + 24 + k32);
            float f1k2 = ldv(f1, n*72 + 48 + k32);
            float rbek = rb1k * ek;
            acc[1] = fmaf(s1a0, rbek, acc[1]);
            acc[2] = fmaf(s1a1, rbek, acc[2]);
            acc[3] = fmaf(s1a2, rbek, acc[3]);
            acc[5] = fmaf(ve0, f1k0, acc[5]);
            acc[6] = fmaf(ve0, f1k1, acc[6]);
            acc[7] = fmaf(ve0, f1k2, acc[7]);
            float g3 = rb1k * f0k;
            acc[8]  = fmaf(g3, s1a0, acc[8]);
            acc[9]  = fmaf(g3, s1a1, acc[9]);
            acc[10] = fmaf(g3, s1a2, acc[10]);
            #pragma unroll
            for (int aa = 0; aa < 3; ++aa) {
              float sa = rb1k * ((aa==0)?s1a0:(aa==1)?s1a1:s1a2);
              acc[11+aa*3+0] = fmaf(sa, f1k0, acc[11+aa*3+0]);
              acc[11+aa*3+1] = fmaf(sa, f1k1, acc[11+aa*3+1]);
              acc[11+aa*3+2] = fmaf(sa, f1k2, acc[11+aa*3+2]);
            }
          }
        }
      }
    } else if (wv == 1) {
      for (int base = 0; base < nch; base += 8) {
        #pragma unroll
        for (int u = 0; u < 2; ++u) {
          int idx = base + 4*u + e4;
          float w = (idx < nch) ? 1.f : 0.f;
          int ic  = (idx < nch) ? idx : 0;
          int2 en = sel[ic];
          int e = en.x, n = en.y;
          float s0 = ldv(sh0, e);
          float s1a[3];
          #pragma unroll
          for (int m = 0; m < 3; ++m) s1a[m] = ldv(sh1, e*3+m);
          float s2a[5];
          #pragma unroll
          for (int m = 0; m < 5; ++m) s2a[m] = ldv(sh2, e*5+m);
          float rb0k = ldv(rb0, e*32 + k16) * w;
          float rb1k = ldv(rb1, e*24 + k16) * w;
          float rb2k = ldv(rb2, e*16 + k16) * w;
          float ek   = ldv(emb, n*32 + k16);
          float f2k[5];
          #pragma unroll
          for (int b = 0; b < 5; ++b) f2k[b] = ldv(f2, n*80 + b*16 + k16);
          float re = rb2k * ek;
          #pragma unroll
          for (int m = 0; m < 5; ++m) acc[m] = fmaf(s2a[m], re, acc[m]);
          float ve0 = s0 * rb0k;
          #pragma unroll
          for (int b = 0; b < 5; ++b) acc[5+b] = fmaf(ve0, f2k[b], acc[5+b]);
          #pragma unroll
          for (int aa = 0; aa < 3; ++aa) {
            float sa = rb1k * s1a[aa];
            #pragma unroll
            for (int b = 0; b < 5; ++b)
              acc[10+aa*5+b] = fmaf(sa, f2k[b], acc[10+aa*5+b]);
          }
        }
      }
    } else if (wv == 2) {
      for (int base = 0; base < nch; base += 8) {
        #pragma unroll
        for (int u = 0; u < 2; ++u) {
          int idx = base + 4*u + e4;
          float w = (idx < nch) ? 1.f : 0.f;
          int ic  = (idx < nch) ? idx : 0;
          int2 en = sel[ic];
          int e = en.x, n = en.y;
          float s2a[5];
          #pragma unroll
          for (int m = 0; m < 5; ++m) s2a[m] = ldv(sh2, e*5+m);
          float rb2k = ldv(rb2, e*16 + k16) * w;
          float f0k  = ldv(f0,  n*32 + k16);
          float f1k[3];
          #pragma unroll
          for (int b = 0; b < 3; ++b) f1k[b] = ldv(f1, n*72 + b*24 + k16);
          float g9 = rb2k * f0k;
          #pragma unroll
          for (int aa = 0; aa < 5; ++aa) acc[aa] = fmaf(g9, s2a[aa], acc[aa]);
          #pragma unroll
          for (int aa = 0; aa < 5; ++aa) {
            float sa = rb2k * s2a[aa];
            #pragma unroll
            for (int b = 0; b < 3; ++b)
              acc[5+aa*3+b] = fmaf(sa, f1k[b], acc[5+aa*3+b]);
          }
        }
      }
    } else {
      for (int base = 0; base < nch; base += 8) {
        #pragma unroll
        for (int u = 0; u < 2; ++u) {
          int idx = base + 4*u + e4;
          float w = (idx < nch) ? 1.f : 0.f;
          int ic  = (idx < nch) ? idx : 0;
          int2 en = sel[ic];
          int e = en.x, n = en.y;
          float s2a[5];
          #pragma unroll
          for (int m = 0; m < 5; ++m) s2a[m] = ldv(sh2, e*5+m);
          float rb2k = ldv(rb2, e*16 + k16) * w;
          float f2k[5];
          #pragma unroll
          for (int b = 0; b < 5; ++b) f2k[b] = ldv(f2, n*80 + b*16 + k16);
          #pragma unroll
          for (int aa = 0; aa < 5; ++aa) {
            float sa = rb2k * s2a[aa];
            #pragma unroll
            for (int b = 0; b < 5; ++b)
              acc[aa*5+b] = fmaf(sa, f2k[b], acc[aa*5+b]);
          }
        }
      }
    }
  }

  if (wv == 0) {
    #pragma unroll
    for (int i = 0; i < 20; ++i) acc[i] += __shfl_xor(acc[i], 32);
    const float* C000 = cgf + 0;
    const float* C011 = cgf + 1;
    const float* C101 = cgf + 35;
    const float* C110 = cgf + 44;
    const float* C111 = cgf + 53;
    const float* C112 = cgf + 80;
    float r[16];
    r[0] = C000[0] * acc[4];
    #pragma unroll
    for (int M = 0; M < 3; ++M) {
      float t = 0.f;
      #pragma unroll
      for (int b = 0; b < 3; ++b) t = fmaf(acc[5+b], C011[b*3+M], t);
      r[1+M] = t;
    }
    #pragma unroll
    for (int M = 0; M < 3; ++M) {
      float t = 0.f;
      #pragma unroll
      for (int aa = 0; aa < 3; ++aa) t = fmaf(acc[8+aa], C101[aa*3+M], t);
      r[4+M] = t;
    }
    {
      float t = 0.f;
      #pragma unroll
      for (int q = 0; q < 9; ++q) t = fmaf(acc[11+q], C110[q], t);
      r[7] = t;
    }
    #pragma unroll
    for (int M = 0; M < 3; ++M) {
      float t = 0.f;
      #pragma unroll
      for (int q = 0; q < 9; ++q) t = fmaf(acc[11+q], C111[q*3+M], t);
      r[8+M] = t;
    }
    #pragma unroll
    for (int M = 0; M < 5; ++M) {
      float t = 0.f;
      #pragma unroll
      for (int q = 0; q < 9; ++q) t = fmaf(acc[11+q], C112[q*5+M], t);
      r[11+M] = t;
    }
    acc[4] = r[0];
    #pragma unroll
    for (int M = 0; M < 3; ++M) acc[5+M]  = r[1+M];
    #pragma unroll
    for (int M = 0; M < 3; ++M) acc[8+M]  = r[4+M];
    acc[11] = r[7];
    #pragma unroll
    for (int M = 0; M < 3; ++M) acc[12+M] = r[8+M];
    #pragma unroll
    for (int M = 0; M < 5; ++M) acc[15+M] = r[11+M];
  } else if (wv == 1) {
    #pragma unroll
    for (int i = 0; i < 25; ++i) {
      acc[i] += __shfl_xor(acc[i], 16);
      acc[i] += __shfl_xor(acc[i], 32);
    }
    const float* C022 = cgf + 10;
    const float* C121 = cgf + 125;
    const float* C122 = cgf + 170;
    float r[13];
    #pragma unroll
    for (int M = 0; M < 5; ++M) {
      float t = 0.f;
      #pragma unroll
      for (int b = 0; b < 5; ++b) t = fmaf(acc[5+b], C022[b*5+M], t);
      r[M] = t;
    }
    #pragma unroll
    for (int M = 0; M < 3; ++M) {
      float t = 0.f;
      #pragma unroll
      for (int q = 0; q < 15; ++q) t = fmaf(acc[10+q], C121[q*3+M], t);
      r[5+M] = t;
    }
    #pragma unroll
    for (int M = 0; M < 5; ++M) {
      float t = 0.f;
      #pragma unroll
      for (int q = 0; q < 15; ++q) t = fmaf(acc[10+q], C122[q*5+M], t);
      r[8+M] = t;
    }
    #pragma unroll
    for (int M = 0; M < 5; ++M) acc[5+M]  = r[M];
    #pragma unroll
    for (int M = 0; M < 3; ++M) acc[10+M] = r[5+M];
    #pragma unroll
    for (int M = 0; M < 5; ++M) acc[13+M] = r[8+M];
  } else if (wv == 2) {
    #pragma unroll
    for (int i = 0; i < 20; ++i) {
      acc[i] += __shfl_xor(acc[i], 16);
      acc[i] += __shfl_xor(acc[i], 32);
    }
    const float* C202 = cgf + 245;
    const float* C211 = cgf + 270;
    const float* C212 = cgf + 315;
    float r[13];
    #pragma unroll
    for (int M = 0; M < 5; ++M) {
      float t = 0.f;
      #pragma unroll
      for (int aa = 0; aa < 5; ++aa) t = fmaf(acc[aa], C202[aa*5+M], t);
      r[M] = t;
    }
    #pragma unroll
    for (int M = 0; M < 3; ++M) {
      float t = 0.f;
      #pragma unroll
      for (int q = 0; q < 15; ++q) t = fmaf(acc[5+q], C211[q*3+M], t);
      r[5+M] = t;
    }
    #pragma unroll
    for (int M = 0; M < 5; ++M) {
      float t = 0.f;
      #pragma unroll
      for (int q = 0; q < 15; ++q) t = fmaf(acc[5+q], C212[q*5+M], t);
      r[8+M] = t;
    }
    #pragma unroll
    for (int M = 0; M < 5; ++M) acc[M]   = r[M];
    #pragma unroll
    for (int M = 0; M < 3; ++M) acc[5+M] = r[5+M];
    #pragma unroll
    for (int M = 0; M < 5; ++M) acc[8+M] = r[8+M];
  } else {
    #pragma unroll
    for (int i = 0; i < 25; ++i) {
      acc[i] += __shfl_xor(acc[i], 16);
      acc[i] += __shfl_xor(acc[i], 32);
    }
    const float* C220 = cgf + 390;
    const float* C221 = cgf + 415;
    const float* C222 = cgf + 490;
    float r[9];
    {
      float t = 0.f;
      #pragma unroll
      for (int q = 0; q < 25; ++q) t = fmaf(acc[q], C220[q], t);
      r[0] = t;
    }
    #pragma unroll
    for (int M = 0; M < 3; ++M) {
      float t = 0.f;
      #pragma unroll
      for (int q = 0; q < 25; ++q) t = fmaf(acc[q], C221[q*3+M], t);
      r[1+M] = t;
    }
    #pragma unroll
    for (int M = 0; M < 5; ++M) {
      float t = 0.f;
      #pragma unroll
      for (int q = 0; q < 25; ++q) t = fmaf(acc[q], C222[q*5+M], t);
      r[4+M] = t;
    }
    #pragma unroll
    for (int i = 0; i < 9; ++i) acc[i] = r[i];
  }

  if constexpr (MODE == 1) {
    if (wv == 0) {
      if (lane < 32) {
        stv(out, O0 + a*32 + k32, acc[0]);
        atomicAdd(&s1r[k32], acc[4]*acc[4]);
        if (k32 < 24) {
          #pragma unroll
          for (int m = 0; m < 3; ++m) stv(out, O1 + a*72 + m*24 + k32, acc[1+m]);
          atomicAdd(&s1r[32+k32], acc[11]*acc[11]);
          float q;
          q = acc[5]*acc[5]+acc[6]*acc[6]+acc[7]*acc[7];
          atomicAdd(&s1r[72+k32], q);
          q = acc[8]*acc[8]+acc[9]*acc[9]+acc[10]*acc[10];
          atomicAdd(&s1r[96+k32], q);
          q = acc[12]*acc[12]+acc[13]*acc[13]+acc[14]*acc[14];
          atomicAdd(&s1r[152+k32], q);
          q = acc[15]*acc[15]+acc[16]*acc[16]+acc[17]*acc[17]
            + acc[18]*acc[18]+acc[19]*acc[19];
          atomicAdd(&s1r[208+k32], q);
        }
      }
    } else if (wv == 1) {
      if (lane < 16) {
        #pragma unroll
        for (int m = 0; m < 5; ++m) stv(out, O2 + a*80 + m*16 + k16, acc[m]);
        float q;
        q = acc[5]*acc[5]+acc[6]*acc[6]+acc[7]*acc[7]+acc[8]*acc[8]+acc[9]*acc[9];
        atomicAdd(&s1r[192+k16], q);
        q = acc[10]*acc[10]+acc[11]*acc[11]+acc[12]*acc[12];
        atomicAdd(&s1r[120+k16], q);
        q = acc[13]*acc[13]+acc[14]*acc[14]+acc[15]*acc[15]
          + acc[16]*acc[16]+acc[17]*acc[17];
        atomicAdd(&s1r[264+k16], q);
      }
    } else if (wv == 2) {
      if (lane < 16) {
        float q;
        q = acc[0]*acc[0]+acc[1]*acc[1]+acc[2]*acc[2]+acc[3]*acc[3]+acc[4]*acc[4];
        atomicAdd(&s1r[232+k16], q);
        q = acc[5]*acc[5]+acc[6]*acc[6]+acc[7]*acc[7];
        atomicAdd(&s1r[136+k16], q);
        q = acc[8]*acc[8]+acc[9]*acc[9]+acc[10]*acc[10]
          + acc[11]*acc[11]+acc[12]*acc[12];
        atomicAdd(&s1r[280+k16], q);
      }
    } else {
      if (lane < 16) {
        atomicAdd(&s1r[56+k16], acc[0]*acc[0]);
        float q;
        q = acc[1]*acc[1]+acc[2]*acc[2]+acc[3]*acc[3];
        atomicAdd(&s1r[176+k16], q);
        q = acc[4]*acc[4]+acc[5]*acc[5]+acc[6]*acc[6]
          + acc[7]*acc[7]+acc[8]*acc[8];
        atomicAdd(&s1r[248+k16], q);
      }
    }
  }

  if constexpr (MODE == 2) {
    if (wv == 0) {
      if (lane < 32) {
        L[k32] = acc[4]*inv[k32];
        if (k32 < 24) {
          L[32+k32] = acc[11]*inv[32+k32];
          #pragma unroll
          for (int M = 0; M < 3; ++M) L[72+M*80+k32]     = acc[5+M]*inv[72+k32];
          #pragma unroll
          for (int M = 0; M < 3; ++M) L[72+M*80+24+k32]  = acc[8+M]*inv[96+k32];
          #pragma unroll
          for (int M = 0; M < 3; ++M) L[312+M*40+k32]    = acc[12+M]*inv[152+k32];
          #pragma unroll
          for (int M = 0; M < 5; ++M) L[432+M*72+16+k32] = acc[15+M]*inv[208+k32];
        }
      }
    } else if (wv == 1) {
      if (lane < 16) {
        #pragma unroll
        for (int M = 0; M < 5; ++M) L[432+M*72+k16]    = acc[5+M]*inv[192+k16];
        #pragma unroll
        for (int M = 0; M < 3; ++M) L[72+M*80+48+k16]  = acc[10+M]*inv[120+k16];
        #pragma unroll
        for (int M = 0; M < 5; ++M) L[792+M*32+k16]    = acc[13+M]*inv[264+k16];
      }
    } else if (wv == 2) {
      if (lane < 16) {
        #pragma unroll
        for (int M = 0; M < 5; ++M) L[432+M*72+40+k16] = acc[0+M]*inv[232+k16];
        #pragma unroll
        for (int M = 0; M < 3; ++M) L[72+M*80+64+k16]  = acc[5+M]*inv[136+k16];
        #pragma unroll
        for (int M = 0; M < 5; ++M) L[792+M*32+16+k16] = acc[8+M]*inv[280+k16];
      }
    } else {
      if (lane < 16) {
        L[56+k16] = acc[0]*inv[56+k16];
        #pragma unroll
        for (int M = 0; M < 3; ++M) L[312+M*40+24+k16] = acc[1+M]*inv[176+k16];
        #pragma unroll
        for (int M = 0; M < 5; ++M) L[432+M*72+56+k16] = acc[4+M]*inv[248+k16];
      }
    }
    __syncthreads();
    int t = threadIdx.x;
    float y2[5] = {0.f,0.f,0.f,0.f,0.f};
    for (int tau = t; tau < 336; tau += 256) {
      int ls = 0;
      while (tau >= c_cum[ls+1]) ++ls;
      int rem = tau - c_cum[ls];
      int kn = c_kout[ls], fin = c_fin[ls];
      int M = rem / kn, ko = rem - M*kn;
      const T* W = (const T*)lp.W[ls];
      float y = ldv((const T*)lp.B[ls], ko);
      const float* xv = &L[c_xb[ls] + M*fin];
      for (int f = 0; f < fin; ++f) y = fmaf(xv[f], ldv(W, f*kn+ko), y);
      stv(out, c_yoff[ls] + (a*c_Ms[ls] + M)*kn + ko, y);
      y2[ls] += y*y;
    }
    #pragma unroll
    for (int i = 0; i < 5; ++i) {
      y2[i] += __shfl_xor(y2[i], 1);  y2[i] += __shfl_xor(y2[i], 2);
      y2[i] += __shfl_xor(y2[i], 4);  y2[i] += __shfl_xor(y2[i], 8);
      y2[i] += __shfl_xor(y2[i], 16); y2[i] += __shfl_xor(y2[i], 32);
    }
    if (lane == 0) {
      #pragma unroll
      for (int i = 0; i < 5; ++i) red[wv][i] = y2[i];
    }
    __syncthreads();
    if (t == 0) {
      #pragma unroll
      for (int i = 0; i < 5; ++i)
        atomicAdd(&s2p[i*64 + ab], red[0][i]+red[1][i]+red[2][i]+red[3][i]);
    }
  }
}

extern "C" void kernel_launch(void* const* d_in, const int* in_sizes, int n_in,
                              void* d_out, int out_size, void* d_ws, size_t ws_size,
                              hipStream_t stream) {
  float* wsf = (float*)d_ws;
  int*   wsi = (int*)(wsf + SINTS);
  const int* centers   = (const int*)d_in[35];
  const int* neighbors = (const int*)d_in[36];
  bool big = ws_size >= (size_t)BIG_FLOATS * 4;

  // Host-side dtype detection (optimization only; kernels flag-gate if -1)
  int know = -1;
  if (in_sizes) {
    long long nb = (long long)in_sizes[0];         // rb0: 200000*32 elems
    if (nb == (long long)N_EDGES*32*2) know = 0;
    else if (nb == (long long)N_EDGES*32*4) know = 1;
  }
  if (know < 0) {
    long long ob = (long long)out_size;            // 5.2M output elems
    if (ob == (long long)OUT_ELEMS*2) know = 0;
    else if (ob == (long long)OUT_ELEMS*4) know = 1;
  }

  Ptrs15 cg;
  for (int i = 0; i < 15; ++i) cg.p[i] = d_in[10+i];
  LinP lp;
  lp.W[0] = d_in[25]; lp.B[0] = d_in[26];
  lp.W[1] = d_in[27]; lp.B[1] = d_in[28];
  lp.W[2] = d_in[29]; lp.B[2] = d_in[30];
  lp.W[3] = d_in[31]; lp.B[3] = d_in[32];
  lp.W[4] = d_in[33]; lp.B[4] = d_in[34];

  const int* flag = wsi + IFLAG;
  const int2* el2 = (const int2*)(wsi + IELIST);

  k_zero<<<156, 256, 0, stream>>>(wsf, wsi,
                                  (const unsigned short*)d_in[0],
                                  (const unsigned short*)d_in[6], cg, know);
  k_hist<<<(N_EDGES+255)/256, 256, 0, stream>>>(centers, wsi+ICOUNT);
  k_scan<<<1, 1024, 0, stream>>>(wsi+ICOUNT, wsi+IOFFS);
  k_scatter2<<<(N_EDGES+255)/256, 256, 0, stream>>>(centers, neighbors, wsi+IOFFS,
                                                    wsi+ICURS, (int2*)(wsi+IELIST));
  if (know < 0) {
    k_cg<bf16 ><<<3, 256, 0, stream>>>(cg, wsf, flag);
    k_cg<float><<<3, 256, 0, stream>>>(cg, wsf, flag);
  }

  if (big) {
    if (know != 1)
      k_role<bf16><<<N_ATOMS, 320, 0, stream>>>((const bf16*)d_in[0], (const bf16*)d_in[1],
          (const bf16*)d_in[2], (const bf16*)d_in[3], (const bf16*)d_in[4], (const bf16*)d_in[5],
          (const bf16*)d_in[6], (const bf16*)d_in[7], (const bf16*)d_in[8], (const bf16*)d_in[9],
          el2, wsi+IOFFS, wsf+SCG, wsf+SS1P, wsf+SXACC, (bf16*)d_out, flag);
    if (know != 0)
      k_role<float><<<N_ATOMS, 320, 0, stream>>>((const float*)d_in[0], (const float*)d_in[1],
          (const float*)d_in[2], (const float*)d_in[3], (const float*)d_in[4], (const float*)d_in[5],
          (const float*)d_in[6], (const float*)d_in[7], (const float*)d_in[8], (const float*)d_in[9],
          el2, wsi+IOFFS, wsf+SCG, wsf+SS1P, wsf+SXACC, (float*)d_out, flag);
    k_red1<<<296, 64, 0, stream>>>(wsf+SS1P, wsf+SINV);
    k_lin<<<N_ATOMS, 256, 0, stream>>>(wsf+SXACC, wsf+SINV, lp, d_out, wsf+SS2P,
                                       flag, know);
    k_scale<<<(3360000+255)/256, 256, 0, stream>>>(wsf+SS2P, d_out, flag, know);
  } else {
    // small-ws fallback: flag-gated dual chain (proven code, normally unused)
    k_main<bf16,1><<<N_ATOMS, 256, 0, stream>>>((const bf16*)d_in[0], (const bf16*)d_in[1],
        (const bf16*)d_in[2], (const bf16*)d_in[3], (const bf16*)d_in[4], (const bf16*)d_in[5],
        (const bf16*)d_in[6], (const bf16*)d_in[7], (const bf16*)d_in[8], (const bf16*)d_in[9],
        el2, wsi+IOFFS, wsf+SCG, wsf+SS1P, nullptr, nullptr, lp, (bf16*)d_out, flag);
    k_main<float,1><<<N_ATOMS, 256, 0, stream>>>((const float*)d_in[0], (const float*)d_in[1],
        (const float*)d_in[2], (const float*)d_in[3], (const float*)d_in[4], (const float*)d_in[5],
        (const float*)d_in[6], (const float*)d_in[7], (const float*)d_in[8], (const float*)d_in[9],
        el2, wsi+IOFFS, wsf+SCG, wsf+SS1P, nullptr, nullptr, lp, (float*)d_out, flag);
    k_red1<<<296, 64, 0, stream>>>(wsf+SS1P, wsf+SINV);
    k_main<bf16,2><<<N_ATOMS, 256, 0, stream>>>((const bf16*)d_in[0], (const bf16*)d_in[1],
        (const bf16*)d_in[2], (const bf16*)d_in[3], (const bf16*)d_in[4], (const bf16*)d_in[5],
        (const bf16*)d_in[6], (const bf16*)d_in[7], (const bf16*)d_in[8], (const bf16*)d_in[9],
        el2, wsi+IOFFS, wsf+SCG, nullptr, wsf+SINV, wsf+SS2P, lp, (bf16*)d_out, flag);
    k_main<float,2><<<N_ATOMS, 256, 0, stream>>>((const float*)d_in[0], (const float*)d_in[1],
        (const float*)d_in[2], (const float*)d_in[3], (const float*)d_in[4], (const float*)d_in[5],
        (const float*)d_in[6], (const float*)d_in[7], (const float*)d_in[8], (const float*)d_in[9],
        el2, wsi+IOFFS, wsf+SCG, nullptr, wsf+SINV, wsf+SS2P, lp, (float*)d_out, flag);
    k_scale<<<(3360000+255)/256, 256, 0, stream>>>(wsf+SS2P, d_out, flag, know);
  }
}